// Round 5
// baseline (449.823 us; speedup 1.0000x reference)
//
#include <hip/hip_runtime.h>
#include <math.h>

#define NB 512
#define NPQ 128
#define NY 1024
#define NO 256
#define NTOT 1408   // NPQ+NY+NO

typedef __attribute__((ext_vector_type(8))) short bf16x8;
typedef __attribute__((ext_vector_type(4))) float f32x4;

__device__ __forceinline__ unsigned short f2bf(float f) {
    unsigned int u = __float_as_uint(f);
    u += 0x7fffu + ((u >> 16) & 1u);   // RTNE
    return (unsigned short)(u >> 16);
}

union U8 { bf16x8 v; unsigned long long u[2]; };

// ============================================================================
// Fused encoder + flash attention. One block per batch. 4 waves x 32 q.
// Per 64-key tile: layer-1 (VALU) -> sH; encode MFMA (A=w2-cols, B=h1-rows,
// R4-verified) -> write tile into sXr[key][d] AND sXt[d][key]; S-MFMA
// (A=q, B=sXr rows; R3-verified); exp epilogue -> sP; PV-MFMA (A=sP,
// B=sXt; R3-verified). 3 barriers/tile; every LDS write->read crosses a
// barrier (R2 lesson); sH parity-double-buffered (same-wave WAR insurance).
// X / POS never touch HBM.
// ============================================================================
__global__ __launch_bounds__(256, 2) void k_fused(
    const float* __restrict__ pred, const float* __restrict__ prey,
    const float* __restrict__ obst, const float* __restrict__ emb,
    const float* __restrict__ e0w1, const float* __restrict__ e0b1,
    const float* __restrict__ e0w2, const float* __restrict__ e0b2,
    const float* __restrict__ e1w1, const float* __restrict__ e1b1,
    const float* __restrict__ e1w2, const float* __restrict__ e1b2,
    const float* __restrict__ e2w1, const float* __restrict__ e2b1,
    const float* __restrict__ e2w2, const float* __restrict__ e2b2,
    const float* __restrict__ QT, const float* __restrict__ QP,
    const float* __restrict__ QC, float* __restrict__ OPRE)
{
    const int tid = threadIdx.x, b = blockIdx.x;
    const int w = tid >> 6, lane = tid & 63, lq = lane & 15, quad = lane >> 4;

    __shared__ __align__(16) short sH[4][2][16][68];  // [wave][parity][row][k]
    __shared__ __align__(16) short sXr[64][68];       // [key][d]
    __shared__ __align__(16) short sXt[64][68];       // [d][key]
    __shared__ __align__(16) short sP[4][32][68];     // [wave][q][key]
    __shared__ float sPos[2][64];                     // [coord][key]

    // ---- Q fragments: wave owns q rows w*32 .. w*32+31 (2 m-tiles) ----
    bf16x8 aq[2][2];
    #pragma unroll
    for (int qt = 0; qt < 2; ++qt) {
        const float* qrow = QT + ((size_t)b*NPQ + w*32 + qt*16 + lq)*64;
        #pragma unroll
        for (int kh = 0; kh < 2; ++kh)
            #pragma unroll
            for (int j = 0; j < 8; ++j)
                aq[qt][kh][j] = (short)f2bf(qrow[kh*32 + quad*8 + j]);
    }

    float qcr[2][4], qp0r[2][4], qp1r[2][4], lacc[2][4];
    f32x4 O[2][4];
    #pragma unroll
    for (int qt = 0; qt < 2; ++qt)
        #pragma unroll
        for (int i = 0; i < 4; ++i) {
            const size_t g = (size_t)b*NPQ + w*32 + qt*16 + quad*4 + i;
            qcr[qt][i]  = QC[g];
            qp0r[qt][i] = -QP[2*g];
            qp1r[qt][i] = -QP[2*g+1];
            lacc[qt][i] = 0.f;
            #pragma unroll
            for (int nt = 0; nt < 4; ++nt) O[qt][nt] = (f32x4){0.f,0.f,0.f,0.f};
        }
    const float E = 0.180336884f;   // (1/sqrt(64)) * log2(e)

    // ---- encoder parameter registers (reloaded at type switches) ----
    const float* st = pred; int cin = 2, nrows = NPQ, roff = 0;
    float w1r0 = 0.f, w1r1 = 0.f, w1r2 = 0.f, b1r = 0.f;
    bf16x8 wfrag[4][2];
    float be[4][4];

    auto load_enc = [&](int type) {
        const float *w1, *b1, *w2, *b2;
        if (type == 0)      { w1=e0w1; b1=e0b1; w2=e0w2; b2=e0b2; st=pred; cin=2; nrows=NPQ; roff=0; }
        else if (type == 1) { w1=e1w1; b1=e1b1; w2=e1w2; b2=e1b2; st=prey; cin=2; nrows=NY;  roff=NPQ; }
        else                { w1=e2w1; b1=e2b1; w2=e2w2; b2=e2b2; st=obst; cin=3; nrows=NO;  roff=NPQ+NY; }
        w1r0 = w1[lane]; w1r1 = w1[64+lane];
        w1r2 = (cin==3) ? w1[128+lane] : 0.f;
        b1r = b1[lane];
        #pragma unroll
        for (int mt = 0; mt < 4; ++mt)
            #pragma unroll
            for (int kh = 0; kh < 2; ++kh)
                #pragma unroll
                for (int j = 0; j < 8; ++j)
                    wfrag[mt][kh][j] = (short)f2bf(w2[(kh*32 + quad*8 + j)*64 + mt*16 + lq]);
        #pragma unroll
        for (int mt = 0; mt < 4; ++mt)
            #pragma unroll
            for (int i = 0; i < 4; ++i)
                be[mt][i] = b2[mt*16 + quad*4 + i] + emb[type*64 + mt*16 + quad*4 + i];
    };

    for (int kt = 0; kt < 22; ++kt) {
        if (kt == 0)       load_enc(0);
        else if (kt == 2)  load_enc(1);
        else if (kt == 18) load_enc(2);
        const int row0 = kt*64 - roff;
        const int par = kt & 1;

        // ---- step 1: layer-1 for the wave's 16 rows -> sH[w][par] ----
        {
            const float* sp = st + ((size_t)b*nrows + row0 + w*16)*cin;
            #pragma unroll
            for (int r = 0; r < 16; ++r) {
                float a = b1r + sp[r*cin]*w1r0 + sp[r*cin+1]*w1r1;
                if (cin == 3) a += sp[r*cin+2]*w1r2;
                sH[w][par][r][lane] = (short)f2bf(fmaxf(a, 0.f));
            }
            if (tid < 128) {
                const int k = tid >> 1, c = tid & 1;
                sPos[c][k] = st[((size_t)b*nrows + row0 + k)*cin + c];
            }
        }
        __syncthreads();   // B2: sH/sPos ready; prev tile's S/PV reads done

        // ---- step 3: encode MFMA -> sXr (row-major) + sXt (transposed) ----
        {
            U8 hb[2];
            #pragma unroll
            for (int kh = 0; kh < 2; ++kh) {
                const short* hp = &sH[w][par][lq][kh*32 + quad*8];
                hb[kh].u[0] = *(const unsigned long long*)hp;
                hb[kh].u[1] = *(const unsigned long long*)(hp + 4);
            }
            const int key = w*16 + lq;
            #pragma unroll
            for (int mt = 0; mt < 4; ++mt) {
                f32x4 ea = (f32x4){0.f,0.f,0.f,0.f};
                ea = __builtin_amdgcn_mfma_f32_16x16x32_bf16(wfrag[mt][0], hb[0].v, ea, 0, 0, 0);
                ea = __builtin_amdgcn_mfma_f32_16x16x32_bf16(wfrag[mt][1], hb[1].v, ea, 0, 0, 0);
                const unsigned short v0 = f2bf(ea[0] + be[mt][0]);
                const unsigned short v1 = f2bf(ea[1] + be[mt][1]);
                const unsigned short v2 = f2bf(ea[2] + be[mt][2]);
                const unsigned short v3 = f2bf(ea[3] + be[mt][3]);
                const int d0 = mt*16 + quad*4;
                *(uint2*)&sXr[key][d0] = make_uint2(
                    (unsigned int)v0 | ((unsigned int)v1 << 16),
                    (unsigned int)v2 | ((unsigned int)v3 << 16));
                sXt[d0  ][key] = (short)v0;
                sXt[d0+1][key] = (short)v1;
                sXt[d0+2][key] = (short)v2;
                sXt[d0+3][key] = (short)v3;
            }
        }
        __syncthreads();   // B4: sXr/sXt ready

        // ---- step 5: S = Q.X^T, exp epilogue -> sP ----
        #pragma unroll
        for (int nt = 0; nt < 4; ++nt) {
            U8 b0, b1x;
            {
                const short* xp = &sXr[nt*16 + lq][quad*8];
                b0.u[0] = *(const unsigned long long*)xp;
                b0.u[1] = *(const unsigned long long*)(xp + 4);
                b1x.u[0] = *(const unsigned long long*)(xp + 32);
                b1x.u[1] = *(const unsigned long long*)(xp + 36);
            }
            const float pos0 = sPos[0][nt*16 + lq];
            const float pos1 = sPos[1][nt*16 + lq];
            #pragma unroll
            for (int qt = 0; qt < 2; ++qt) {
                f32x4 sa = (f32x4){0.f,0.f,0.f,0.f};
                sa = __builtin_amdgcn_mfma_f32_16x16x32_bf16(aq[qt][0], b0.v, sa, 0, 0, 0);
                sa = __builtin_amdgcn_mfma_f32_16x16x32_bf16(aq[qt][1], b1x.v, sa, 0, 0, 0);
                #pragma unroll
                for (int i = 0; i < 4; ++i) {
                    float s = sa[i] + qcr[qt][i];
                    s = fmaf(qp0r[qt][i], pos0, s);
                    s = fmaf(qp1r[qt][i], pos1, s);
                    const float p = exp2f(s * E);
                    lacc[qt][i] += p;
                    sP[w][qt*16 + quad*4 + i][nt*16 + lq] = (short)f2bf(p);
                }
            }
        }
        __syncthreads();   // B6: sP ready

        // ---- step 7: PV accumulate ----
        #pragma unroll
        for (int kc = 0; kc < 2; ++kc) {
            U8 pa[2];
            #pragma unroll
            for (int qt = 0; qt < 2; ++qt) {
                const short* pp = &sP[w][qt*16 + lq][kc*32 + quad*8];
                pa[qt].u[0] = *(const unsigned long long*)pp;
                pa[qt].u[1] = *(const unsigned long long*)(pp + 4);
            }
            #pragma unroll
            for (int nt = 0; nt < 4; ++nt) {
                U8 bv;
                const short* xp = &sXt[nt*16 + lq][kc*32 + quad*8];
                bv.u[0] = *(const unsigned long long*)xp;
                bv.u[1] = *(const unsigned long long*)(xp + 4);
                O[0][nt] = __builtin_amdgcn_mfma_f32_16x16x32_bf16(pa[0].v, bv.v, O[0][nt], 0, 0, 0);
                O[1][nt] = __builtin_amdgcn_mfma_f32_16x16x32_bf16(pa[1].v, bv.v, O[1][nt], 0, 0, 0);
            }
        }
    }

    // ---- epilogue: reduce l over the 16 n-lanes, write O/l ----
    #pragma unroll
    for (int qt = 0; qt < 2; ++qt)
        #pragma unroll
        for (int i = 0; i < 4; ++i) {
            #pragma unroll
            for (int off = 1; off < 16; off <<= 1)
                lacc[qt][i] += __shfl_xor(lacc[qt][i], off);
            const float rl = 1.f / lacc[qt][i];
            float* orow = OPRE + ((size_t)b*NPQ + w*32 + qt*16 + quad*4 + i)*64;
            #pragma unroll
            for (int nt = 0; nt < 4; ++nt) orow[nt*16 + lq] = O[qt][nt][i] * rl;
        }
}

// ============================================================================
// Kernel 2: queries (unchanged from R4 — verified).
// ============================================================================
__global__ __launch_bounds__(256) void k_query(
    const float* __restrict__ pred, const float* __restrict__ emb,
    const float* __restrict__ e0w1, const float* __restrict__ e0b1,
    const float* __restrict__ e0w2, const float* __restrict__ e0b2,
    const float* __restrict__ wq, const float* __restrict__ bq,
    const float* __restrict__ wk, const float* __restrict__ bk,
    const float* __restrict__ wp, const float* __restrict__ bp,
    float* __restrict__ QT, float* __restrict__ QP, float* __restrict__ QC)
{
    const int tid = threadIdx.x, lane = tid & 63, wv = tid >> 6;
    const int p0 = blockIdx.x * 64;
    __shared__ float wbuf[64*65];
    __shared__ float hst[4][8][64];
    __shared__ float xs[64][64];
    __shared__ float qs[64][64];
    float wreg[64];

    for (int i = tid; i < 4096; i += 256) wbuf[(i>>6)*65 + (i&63)] = e0w2[i];
    __syncthreads();
    #pragma unroll
    for (int kk = 0; kk < 64; ++kk) wreg[kk] = wbuf[kk*65 + lane];
    {
        const float w1r0 = e0w1[lane], w1r1 = e0w1[64+lane];
        const float b1r = e0b1[lane];
        const float b2r = e0b2[lane] + emb[lane];
        for (int chunk = 0; chunk < 2; ++chunk) {
            const int r0 = wv*16 + chunk*8;
            const float* sp = pred + (size_t)(p0 + r0)*2;
            float h1[8];
            #pragma unroll
            for (int rr = 0; rr < 8; ++rr)
                h1[rr] = fmaxf(b1r + sp[rr*2]*w1r0 + sp[rr*2+1]*w1r1, 0.f);
            #pragma unroll
            for (int rr = 0; rr < 8; ++rr) hst[wv][rr][lane] = h1[rr];
            float acc[8];
            #pragma unroll
            for (int rr = 0; rr < 8; ++rr) acc[rr] = b2r;
            #pragma unroll
            for (int kk = 0; kk < 64; kk += 4) {
                #pragma unroll
                for (int rr = 0; rr < 8; ++rr) {
                    const float4 hb = *(const float4*)&hst[wv][rr][kk];
                    acc[rr] = fmaf(hb.x, wreg[kk],   acc[rr]);
                    acc[rr] = fmaf(hb.y, wreg[kk+1], acc[rr]);
                    acc[rr] = fmaf(hb.z, wreg[kk+2], acc[rr]);
                    acc[rr] = fmaf(hb.w, wreg[kk+3], acc[rr]);
                }
            }
            #pragma unroll
            for (int rr = 0; rr < 8; ++rr) xs[r0+rr][lane] = acc[rr];
        }
    }
    __syncthreads();
    for (int i = tid; i < 4096; i += 256) wbuf[(i>>6)*65 + (i&63)] = wq[i];
    __syncthreads();
    #pragma unroll
    for (int kk = 0; kk < 64; ++kk) wreg[kk] = wbuf[kk*65 + lane];
    {
        const float bqr = bq[lane];
        for (int chunk = 0; chunk < 2; ++chunk) {
            const int r0 = wv*16 + chunk*8;
            float acc[8];
            #pragma unroll
            for (int rr = 0; rr < 8; ++rr) acc[rr] = bqr;
            #pragma unroll
            for (int kk = 0; kk < 64; kk += 4) {
                #pragma unroll
                for (int rr = 0; rr < 8; ++rr) {
                    const float4 xb = *(const float4*)&xs[r0+rr][kk];
                    acc[rr] = fmaf(xb.x, wreg[kk],   acc[rr]);
                    acc[rr] = fmaf(xb.y, wreg[kk+1], acc[rr]);
                    acc[rr] = fmaf(xb.z, wreg[kk+2], acc[rr]);
                    acc[rr] = fmaf(xb.w, wreg[kk+3], acc[rr]);
                }
            }
            #pragma unroll
            for (int rr = 0; rr < 8; ++rr) qs[r0+rr][lane] = acc[rr];
        }
    }
    __syncthreads();
    for (int i = tid; i < 4096; i += 256) wbuf[(i>>6)*65 + (i&63)] = wk[i];
    __syncthreads();
    #pragma unroll
    for (int kk = 0; kk < 64; ++kk) wreg[kk] = wbuf[lane*65 + kk];  // row `lane` of wk
    {
        const float wp0r = wp[lane], wp1r = wp[64+lane];
        const float bpkr = bp[lane] + bk[lane];
        for (int chunk = 0; chunk < 2; ++chunk) {
            const int r0 = wv*16 + chunk*8;
            float acc[8];
            #pragma unroll
            for (int rr = 0; rr < 8; ++rr) acc[rr] = 0.f;
            #pragma unroll
            for (int kk = 0; kk < 64; kk += 4) {
                #pragma unroll
                for (int rr = 0; rr < 8; ++rr) {
                    const float4 qb = *(const float4*)&qs[r0+rr][kk];
                    acc[rr] = fmaf(qb.x, wreg[kk],   acc[rr]);
                    acc[rr] = fmaf(qb.y, wreg[kk+1], acc[rr]);
                    acc[rr] = fmaf(qb.z, wreg[kk+2], acc[rr]);
                    acc[rr] = fmaf(qb.w, wreg[kk+3], acc[rr]);
                }
            }
            #pragma unroll
            for (int rr = 0; rr < 8; ++rr)
                QT[(size_t)(p0 + r0 + rr)*64 + lane] = acc[rr];
            const float* sp = pred + (size_t)(p0 + r0)*2;
            #pragma unroll
            for (int rr = 0; rr < 8; ++rr) {
                const float qv = qs[r0+rr][lane];
                float v0 = qv * wp0r, v1 = qv * wp1r, v2 = qv * bpkr;
                #pragma unroll
                for (int o = 32; o > 0; o >>= 1) {
                    v0 += __shfl_xor(v0, o);
                    v1 += __shfl_xor(v1, o);
                    v2 += __shfl_xor(v2, o);
                }
                if (lane == 0) {
                    const int p = p0 + r0 + rr;
                    QP[(size_t)p*2]   = v0;
                    QP[(size_t)p*2+1] = v1;
                    QC[p] = v0*sp[rr*2] + v1*sp[rr*2+1] + v2;
                }
            }
        }
    }
}

// ============================================================================
// Kernel 4: output head (unchanged from R4 — verified).
// ============================================================================
__global__ __launch_bounds__(256) void k_head(
    const float* __restrict__ OPRE,
    const float* __restrict__ wv, const float* __restrict__ bv,
    const float* __restrict__ wo, const float* __restrict__ bo,
    const float* __restrict__ nw1, const float* __restrict__ nb1,
    const float* __restrict__ nw2, const float* __restrict__ nb2,
    const float* __restrict__ nw3, const float* __restrict__ nb3,
    float* __restrict__ OUT)
{
    const int tid = threadIdx.x, lane = tid & 63, wv4 = tid >> 6;
    const int p0 = blockIdx.x * 64;
    __shared__ float wbuf[64*65];
    __shared__ float sa[64][64];
    __shared__ float sb[64][64];

    for (int i = tid; i < 4096; i += 256) sa[i>>6][i&63] = OPRE[(size_t)p0*64 + i];

    for (int l = 0; l < 4; ++l) {
        __syncthreads();
        const float *W, *Bb;
        if (l==0)      { W=wv;  Bb=bv;  }
        else if (l==1) { W=wo;  Bb=bo;  }
        else if (l==2) { W=nw1; Bb=nb1; }
        else           { W=nw2; Bb=nb2; }
        for (int i = tid; i < 4096; i += 256) wbuf[(i>>6)*65 + (i&63)] = W[i];
        __syncthreads();
        float wreg[64];
        #pragma unroll
        for (int kk = 0; kk < 64; ++kk) wreg[kk] = wbuf[kk*65 + lane];
        const float br = Bb[lane];
        const bool doRelu = (l >= 2);
        float (*src)[64] = (l & 1) ? sb : sa;
        float (*dst)[64] = (l & 1) ? sa : sb;
        for (int chunk = 0; chunk < 2; ++chunk) {
            const int r0 = wv4*16 + chunk*8;
            float acc[8];
            #pragma unroll
            for (int rr=0;rr<8;++rr) acc[rr] = br;
            #pragma unroll
            for (int kk = 0; kk < 64; kk += 4) {
                #pragma unroll
                for (int rr = 0; rr < 8; ++rr) {
                    const float4 xb = *(const float4*)&src[r0+rr][kk];
                    acc[rr] = fmaf(xb.x, wreg[kk],   acc[rr]);
                    acc[rr] = fmaf(xb.y, wreg[kk+1], acc[rr]);
                    acc[rr] = fmaf(xb.z, wreg[kk+2], acc[rr]);
                    acc[rr] = fmaf(xb.w, wreg[kk+3], acc[rr]);
                }
            }
            #pragma unroll
            for (int rr=0;rr<8;++rr)
                dst[r0+rr][lane] = doRelu ? fmaxf(acc[rr],0.f) : acc[rr];
        }
    }
    __syncthreads();
    const float w3r = nw3[lane];
    const float b3 = nb3[0];
    for (int chunk = 0; chunk < 2; ++chunk) {
        const int r0 = wv4*16 + chunk*8;
        #pragma unroll
        for (int rr=0;rr<8;++rr) {
            float v = sa[r0+rr][lane] * w3r;
            #pragma unroll
            for (int o=32;o>0;o>>=1) v += __shfl_xor(v, o);
            if (lane == 0) OUT[p0 + r0 + rr] = tanhf(v + b3);
        }
    }
}

// ============================================================================
extern "C" void kernel_launch(void* const* d_in, const int* in_sizes, int n_in,
                              void* d_out, int out_size, void* d_ws, size_t ws_size,
                              hipStream_t stream)
{
    const float* pred = (const float*)d_in[0];
    const float* prey = (const float*)d_in[1];
    const float* obst = (const float*)d_in[2];
    const float* emb  = (const float*)d_in[4];
    const float* e0w1 = (const float*)d_in[5];
    const float* e0b1 = (const float*)d_in[6];
    const float* e0w2 = (const float*)d_in[7];
    const float* e0b2 = (const float*)d_in[8];
    const float* e1w1 = (const float*)d_in[9];
    const float* e1b1 = (const float*)d_in[10];
    const float* e1w2 = (const float*)d_in[11];
    const float* e1b2 = (const float*)d_in[12];
    const float* e2w1 = (const float*)d_in[13];
    const float* e2b1 = (const float*)d_in[14];
    const float* e2w2 = (const float*)d_in[15];
    const float* e2b2 = (const float*)d_in[16];
    const float* wq  = (const float*)d_in[17];
    const float* bq  = (const float*)d_in[18];
    const float* wk  = (const float*)d_in[19];
    const float* bk  = (const float*)d_in[20];
    const float* wvv = (const float*)d_in[21];
    const float* bv  = (const float*)d_in[22];
    const float* wp  = (const float*)d_in[23];
    const float* bp  = (const float*)d_in[24];
    const float* wo  = (const float*)d_in[25];
    const float* bo  = (const float*)d_in[26];
    const float* nw1 = (const float*)d_in[27];
    const float* nb1 = (const float*)d_in[28];
    const float* nw2 = (const float*)d_in[29];
    const float* nb2 = (const float*)d_in[30];
    const float* nw3 = (const float*)d_in[31];
    const float* nb3 = (const float*)d_in[32];

    float* ws = (float*)d_ws;
    float* QT   = ws;                // 512*128*64 = 4,194,304 f32
    float* QP   = QT + 4194304;      // 512*128*2
    float* QC   = QP + 131072;       // 512*128
    float* OPRE = QC + 65536;        // 512*128*64
    // total ~34 MB

    k_query<<<1024, 256, 0, stream>>>(pred, emb, e0w1,e0b1,e0w2,e0b2,
        wq,bq, wk,bk, wp,bp, QT,QP,QC);
    k_fused<<<512, 256, 0, stream>>>(pred, prey, obst, emb,
        e0w1,e0b1,e0w2,e0b2, e1w1,e1b1,e1w2,e1b2, e2w1,e2b1,e2w2,e2b2,
        QT, QP, QC, OPRE);
    k_head<<<1024, 256, 0, stream>>>(OPRE, wvv,bv, wo,bo, nw1,nb1, nw2,nb2, nw3,nb3,
        (float*)d_out);
}

// Round 6
// 374.030 us; speedup vs baseline: 1.2026x; 1.2026x over previous
//
#include <hip/hip_runtime.h>
#include <math.h>

#define NB 512
#define NPQ 128
#define NY 1024
#define NO 256
#define NTOT 1408   // NPQ+NY+NO

typedef __attribute__((ext_vector_type(8))) short bf16x8;
typedef __attribute__((ext_vector_type(4))) float f32x4;

__device__ __forceinline__ unsigned short f2bf(float f) {
    unsigned int u = __float_as_uint(f);
    u += 0x7fffu + ((u >> 16) & 1u);   // RTNE
    return (unsigned short)(u >> 16);
}
__device__ __forceinline__ float bf2f(short s) {
    return __uint_as_float(((unsigned int)(unsigned short)s) << 16);
}

union U8 { bf16x8 v; unsigned long long u[2]; };

// ============================================================================
// Kernel 0: fold weights. Aqk = e0w2@wq@wk^T (so qtil = h1@Aqk + a0),
// P3 rows = [qp0|qp1|qs] generators, W_vo = wv@wo, b_vo = bv@wo+bo.
// One block; ~800k MACs total.
// ============================================================================
__global__ __launch_bounds__(256) void k_prep(
    const float* __restrict__ emb,  const float* __restrict__ e0b2,
    const float* __restrict__ e0w2, const float* __restrict__ wq,
    const float* __restrict__ bq,   const float* __restrict__ wk,
    const float* __restrict__ bk,   const float* __restrict__ wp,
    const float* __restrict__ bp,   const float* __restrict__ wvv,
    const float* __restrict__ bv,   const float* __restrict__ wo,
    const float* __restrict__ bo,
    float* __restrict__ Aqk, float* __restrict__ a0, float* __restrict__ P3,
    float* __restrict__ b0g0, float* __restrict__ Wvo, float* __restrict__ bvo)
{
    const int tid = threadIdx.x;
    __shared__ float sW2q[4096];   // W2q[h][j] = sum_e e0w2[h][e] wq[e][j]
    __shared__ float scq[64];      // c_q[j]    = sum_e (e0b2+emb0)[e] wq[e][j] + bq[j]

    for (int idx = tid; idx < 4096; idx += 256) {
        const int h = idx >> 6, j = idx & 63;
        float s = 0.f;
        for (int e = 0; e < 64; ++e) s += e0w2[h*64+e] * wq[e*64+j];
        sW2q[idx] = s;
    }
    if (tid < 64) {
        const int j = tid;
        float s = bq[j];
        for (int e = 0; e < 64; ++e) s += (e0b2[e] + emb[e]) * wq[e*64+j];
        scq[j] = s;
    }
    // W_vo / b_vo (independent of W2q)
    for (int idx = tid; idx < 4096; idx += 256) {
        const int e = idx >> 6, o = idx & 63;
        float s = 0.f;
        for (int d = 0; d < 64; ++d) s += wvv[e*64+d] * wo[d*64+o];
        Wvo[idx] = s;
    }
    if (tid < 64) {
        const int o = tid;
        float s = bo[o];
        for (int d = 0; d < 64; ++d) s += bv[d] * wo[d*64+o];
        bvo[o] = s;
    }
    __syncthreads();
    // Aqk[h][d] = sum_j W2q[h][j] wk[d][j]
    for (int idx = tid; idx < 4096; idx += 256) {
        const int h = idx >> 6, d = idx & 63;
        float s = 0.f;
        for (int j = 0; j < 64; ++j) s += sW2q[h*64+j] * wk[d*64+j];
        Aqk[h*64+d] = s;
    }
    if (tid < 64) {
        const int d = tid;
        float s = 0.f;
        for (int j = 0; j < 64; ++j) s += scq[j] * wk[d*64+j];
        a0[d] = s;
    }
    // P3[c][h]: c=0,1 -> Bp[h][c] = sum_j W2q[h][j] wp[c][j]; c=2 -> g[h]; else 0
    for (int i = tid; i < 1024; i += 256) {
        const int c = i >> 6, h = i & 63;
        float s = 0.f;
        if (c == 0 || c == 1) {
            for (int j = 0; j < 64; ++j) s += sW2q[h*64+j] * wp[c*64+j];
        } else if (c == 2) {
            for (int j = 0; j < 64; ++j) s += sW2q[h*64+j] * (bp[j] + bk[j]);
        }
        P3[i] = s;
    }
    if (tid == 0) {
        float s0 = 0.f, s1 = 0.f, s2 = 0.f;
        for (int j = 0; j < 64; ++j) {
            s0 += scq[j] * wp[j];
            s1 += scq[j] * wp[64+j];
            s2 += scq[j] * (bp[j] + bk[j]);
        }
        b0g0[0] = s0; b0g0[1] = s1; b0g0[2] = s2;
    }
}

// ============================================================================
// Kernel 1: entity encoders -> X[B,N,64] (bf16), POS[B,N,2] (f32)
// (byte-identical to R4 — verified)
// ============================================================================
__global__ __launch_bounds__(256) void k_encode(
    const float* __restrict__ pred, const float* __restrict__ prey,
    const float* __restrict__ obst, const float* __restrict__ emb,
    const float* __restrict__ e0w1, const float* __restrict__ e0b1,
    const float* __restrict__ e0w2, const float* __restrict__ e0b2,
    const float* __restrict__ e1w1, const float* __restrict__ e1b1,
    const float* __restrict__ e1w2, const float* __restrict__ e1b2,
    const float* __restrict__ e2w1, const float* __restrict__ e2b1,
    const float* __restrict__ e2w2, const float* __restrict__ e2b2,
    unsigned short* __restrict__ X, float* __restrict__ POS)
{
    const int blk = blockIdx.x;
    int type, lrow0, cin, lsh, nmask, nbase;
    const float *st, *w1, *b1, *w2, *b2;
    if (blk < 512)       { type=0; lrow0=blk*128;        st=pred; w1=e0w1; b1=e0b1; w2=e0w2; b2=e0b2; cin=2; lsh=7;  nmask=NPQ-1; nbase=0; }
    else if (blk < 4608) { type=1; lrow0=(blk-512)*128;  st=prey; w1=e1w1; b1=e1b1; w2=e1w2; b2=e1b2; cin=2; lsh=10; nmask=NY-1;  nbase=NPQ; }
    else                 { type=2; lrow0=(blk-4608)*128; st=obst; w1=e2w1; b1=e2b1; w2=e2w2; b2=e2b2; cin=3; lsh=8;  nmask=NO-1;  nbase=NPQ+NY; }

    const int tid = threadIdx.x, lane = tid & 63, w = tid >> 6;
    const int lq = lane & 15, quad = lane >> 4;

    __shared__ __align__(16) short sH[4][2][16][68];   // [wave][dbuf][row][k] bf16

    bf16x8 wfrag[4][2];
    #pragma unroll
    for (int mt = 0; mt < 4; ++mt)
        #pragma unroll
        for (int kh = 0; kh < 2; ++kh)
            #pragma unroll
            for (int j = 0; j < 8; ++j)
                wfrag[mt][kh][j] = (short)f2bf(w2[(kh*32 + quad*8 + j)*64 + mt*16 + lq]);

    float be[4][4];
    #pragma unroll
    for (int mt = 0; mt < 4; ++mt) {
        const float4 bb4 = *(const float4*)&b2[mt*16 + quad*4];
        const float4 ee4 = *(const float4*)&emb[type*64 + mt*16 + quad*4];
        be[mt][0] = bb4.x + ee4.x; be[mt][1] = bb4.y + ee4.y;
        be[mt][2] = bb4.z + ee4.z; be[mt][3] = bb4.w + ee4.w;
    }

    const float w1r0 = w1[lane], w1r1 = w1[64+lane];
    const float w1r2 = (cin==3) ? w1[128+lane] : 0.f;
    const float b1r = b1[lane];

    {
        const int r = tid >> 1, c = tid & 1;
        const int lr = lrow0 + r;
        const int pb = lr >> lsh, n = nbase + (lr & nmask);
        POS[((size_t)pb*NTOT + n)*2 + c] = st[(size_t)lr*cin + c];
    }

    for (int rt = 0; rt < 2; ++rt) {
        const int r0 = lrow0 + w*32 + rt*16;
        const float* sp = st + (size_t)r0*cin;
        #pragma unroll
        for (int r = 0; r < 16; ++r) {
            float a = b1r + sp[r*cin]*w1r0 + sp[r*cin+1]*w1r1;
            if (cin==3) a += sp[r*cin+2]*w1r2;
            sH[w][rt][r][lane] = (short)f2bf(fmaxf(a, 0.f));
        }
        __syncthreads();

        bf16x8 hb[2];
        #pragma unroll
        for (int kh = 0; kh < 2; ++kh)
            hb[kh] = *(const bf16x8*)&sH[w][rt][lq][kh*32 + quad*8];

        f32x4 acc[4];
        #pragma unroll
        for (int mt = 0; mt < 4; ++mt) acc[mt] = (f32x4){0.f,0.f,0.f,0.f};
        #pragma unroll
        for (int mt = 0; mt < 4; ++mt) {
            acc[mt] = __builtin_amdgcn_mfma_f32_16x16x32_bf16(wfrag[mt][0], hb[0], acc[mt], 0, 0, 0);
            acc[mt] = __builtin_amdgcn_mfma_f32_16x16x32_bf16(wfrag[mt][1], hb[1], acc[mt], 0, 0, 0);
        }

        const int lr = r0 + lq;
        const int bb = lr >> lsh, n = nbase + (lr & nmask);
        unsigned short* xbase = X + ((size_t)bb*NTOT + n)*64;
        #pragma unroll
        for (int mt = 0; mt < 4; ++mt) {
            const unsigned int u0 = (unsigned int)f2bf(acc[mt][0] + be[mt][0])
                                  | ((unsigned int)f2bf(acc[mt][1] + be[mt][1]) << 16);
            const unsigned int u1 = (unsigned int)f2bf(acc[mt][2] + be[mt][2])
                                  | ((unsigned int)f2bf(acc[mt][3] + be[mt][3]) << 16);
            *(uint2*)(xbase + mt*16 + quad*4) = make_uint2(u0, u1);
        }
    }
}

// ============================================================================
// Kernel 2 (R6): queries from folded weights. One block per batch (512).
// layer-1 (VALU, K=2) -> sH; qtil = h1@Aqk + a0 via 4 MFMA m-tiles
// (encode-pattern A/B/D layouts, HW-verified); extra m-tile with P3 gives
// [qp0,qp1,qs] on quad-0 lanes. No shuffle reductions, no big weight stages.
// ============================================================================
__global__ __launch_bounds__(256) void k_query(
    const float* __restrict__ pred,
    const float* __restrict__ e0w1, const float* __restrict__ e0b1,
    const float* __restrict__ Aqk,  const float* __restrict__ a0,
    const float* __restrict__ P3,   const float* __restrict__ b0g0,
    float* __restrict__ QT, float* __restrict__ QP, float* __restrict__ QC)
{
    const int tid = threadIdx.x, b = blockIdx.x;
    const int w = tid >> 6, lane = tid & 63, lq = lane & 15, quad = lane >> 4;
    __shared__ __align__(16) short sH[4][32][68];

    // layer-1: wave w handles rows w*32..w*32+31
    const float w1r0 = e0w1[lane], w1r1 = e0w1[64+lane], b1r = e0b1[lane];
    {
        const float* sp = pred + ((size_t)b*NPQ + w*32)*2;
        #pragma unroll
        for (int r = 0; r < 32; ++r) {
            const float a = b1r + sp[2*r]*w1r0 + sp[2*r+1]*w1r1;
            sH[w][r][lane] = (short)f2bf(fmaxf(a, 0.f));
        }
    }

    // A-frags: Aqk columns (A[m=d][k=h] = Aqk[h][d]) + P3 rows
    bf16x8 wfrag[4][2], a3[2];
    #pragma unroll
    for (int mt = 0; mt < 4; ++mt)
        #pragma unroll
        for (int kh = 0; kh < 2; ++kh)
            #pragma unroll
            for (int j = 0; j < 8; ++j)
                wfrag[mt][kh][j] = (short)f2bf(Aqk[(kh*32 + quad*8 + j)*64 + mt*16 + lq]);
    #pragma unroll
    for (int kh = 0; kh < 2; ++kh)
        #pragma unroll
        for (int j = 0; j < 8; ++j)
            a3[kh][j] = (short)f2bf(P3[lq*64 + kh*32 + quad*8 + j]);

    float4 a0r[4];
    #pragma unroll
    for (int mt = 0; mt < 4; ++mt) a0r[mt] = *(const float4*)&a0[mt*16 + quad*4];
    const float c0 = b0g0[0], c1 = b0g0[1], c2 = b0g0[2];

    __syncthreads();   // sH writes before B-frag reads (R2 lesson)

    for (int bt = 0; bt < 2; ++bt) {
        U8 hb0, hb1;
        const short* hp = &sH[w][bt*16 + lq][0];
        hb0.u[0] = *(const unsigned long long*)(hp + quad*8);
        hb0.u[1] = *(const unsigned long long*)(hp + quad*8 + 4);
        hb1.u[0] = *(const unsigned long long*)(hp + 32 + quad*8);
        hb1.u[1] = *(const unsigned long long*)(hp + 32 + quad*8 + 4);

        f32x4 acc[4], acc3;
        #pragma unroll
        for (int mt = 0; mt < 4; ++mt) acc[mt] = (f32x4){0.f,0.f,0.f,0.f};
        acc3 = (f32x4){0.f,0.f,0.f,0.f};
        #pragma unroll
        for (int mt = 0; mt < 4; ++mt) {
            acc[mt] = __builtin_amdgcn_mfma_f32_16x16x32_bf16(wfrag[mt][0], hb0.v, acc[mt], 0, 0, 0);
            acc[mt] = __builtin_amdgcn_mfma_f32_16x16x32_bf16(wfrag[mt][1], hb1.v, acc[mt], 0, 0, 0);
        }
        acc3 = __builtin_amdgcn_mfma_f32_16x16x32_bf16(a3[0], hb0.v, acc3, 0, 0, 0);
        acc3 = __builtin_amdgcn_mfma_f32_16x16x32_bf16(a3[1], hb1.v, acc3, 0, 0, 0);

        const int row = b*NPQ + w*32 + bt*16 + lq;   // global query index
        #pragma unroll
        for (int mt = 0; mt < 4; ++mt) {
            *(float4*)&QT[(size_t)row*64 + mt*16 + quad*4] = make_float4(
                acc[mt][0] + a0r[mt].x, acc[mt][1] + a0r[mt].y,
                acc[mt][2] + a0r[mt].z, acc[mt][3] + a0r[mt].w);
        }
        if (quad == 0) {
            const float qp0 = acc3[0] + c0, qp1 = acc3[1] + c1, qs = acc3[2] + c2;
            const float p0 = pred[(size_t)row*2], p1 = pred[(size_t)row*2 + 1];
            QP[(size_t)row*2]     = qp0;
            QP[(size_t)row*2 + 1] = qp1;
            QC[row] = qp0*p0 + qp1*p1 + qs;
        }
    }
}

// ============================================================================
// Kernel 3: MFMA flash attention (byte-identical to R4 — verified).
// ============================================================================
__global__ __launch_bounds__(256) void k_attn(
    const unsigned short* __restrict__ X, const float* __restrict__ POS,
    const float* __restrict__ QT, const float* __restrict__ QP,
    const float* __restrict__ QC, float* __restrict__ OPRE)
{
    const int tid = threadIdx.x;
    const int b = blockIdx.x >> 1;
    const int qh = blockIdx.x & 1;
    const int w = tid >> 6, lane = tid & 63, lq = lane & 15, quad = lane >> 4;
    const int qbase = qh*64 + w*16;

    __shared__ __align__(16) short sXc[2][64][68];
    __shared__ __align__(16) short sP[4][16*68];
    __shared__ float sPos[2][2][64];

    const float* qrow = QT + ((size_t)b*NPQ + qbase + lq)*64;
    bf16x8 aq0, aq1;
    #pragma unroll
    for (int j = 0; j < 8; ++j) aq0[j] = (short)f2bf(qrow[quad*8 + j]);
    #pragma unroll
    for (int j = 0; j < 8; ++j) aq1[j] = (short)f2bf(qrow[32 + quad*8 + j]);

    float qcr[4], qp0r[4], qp1r[4], lacc[4];
    f32x4 O[4];
    #pragma unroll
    for (int i = 0; i < 4; ++i) {
        const size_t g = (size_t)b*NPQ + qbase + quad*4 + i;
        qcr[i]  = QC[g];
        qp0r[i] = -QP[2*g];
        qp1r[i] = -QP[2*g+1];
        lacc[i] = 0.f;
        O[i] = (f32x4){0.f, 0.f, 0.f, 0.f};
    }
    const float E = 0.180336884f;   // (1/sqrt(64)) * log2(e)

    const int skey = tid & 63, sd0 = (tid >> 6) * 16;

    {
        const unsigned short* gx = X + ((size_t)b*NTOT + skey)*64 + sd0;
        uint4 t0 = *(const uint4*)(gx);
        uint4 t1 = *(const uint4*)(gx + 8);
        unsigned short tmp[16];
        *(uint4*)tmp = t0; *(uint4*)(tmp+8) = t1;
        #pragma unroll
        for (int j = 0; j < 16; ++j) sXc[0][sd0+j][skey] = (short)tmp[j];
        if (tid < 128)
            sPos[0][tid&1][tid>>1] = POS[((size_t)b*NTOT + (tid>>1))*2 + (tid&1)];
    }
    __syncthreads();

    for (int kt = 0; kt < 22; ++kt) {
        const int bb = kt & 1;
        const bool pf = (kt + 1 < 22);

        uint4 t0, t1; float posreg = 0.f;
        if (pf) {
            const unsigned short* gx = X + ((size_t)b*NTOT + (kt+1)*64 + skey)*64 + sd0;
            t0 = *(const uint4*)(gx);
            t1 = *(const uint4*)(gx + 8);
            if (tid < 128)
                posreg = POS[((size_t)b*NTOT + (kt+1)*64 + (tid>>1))*2 + (tid&1)];
        }

        union U16 { bf16x8 v; uint4 u; };
        U16 bx[4][2];
        #pragma unroll
        for (int nt = 0; nt < 4; ++nt) {
            const unsigned short* xrow = X + ((size_t)b*NTOT + kt*64 + nt*16 + lq)*64;
            bx[nt][0].u = *(const uint4*)(xrow + quad*8);
            bx[nt][1].u = *(const uint4*)(xrow + 32 + quad*8);
        }
        #pragma unroll
        for (int nt = 0; nt < 4; ++nt) {
            f32x4 acc = {0.f, 0.f, 0.f, 0.f};
            acc = __builtin_amdgcn_mfma_f32_16x16x32_bf16(aq0, bx[nt][0].v, acc, 0, 0, 0);
            acc = __builtin_amdgcn_mfma_f32_16x16x32_bf16(aq1, bx[nt][1].v, acc, 0, 0, 0);
            const float pos0 = sPos[bb][0][nt*16 + lq];
            const float pos1 = sPos[bb][1][nt*16 + lq];
            #pragma unroll
            for (int i = 0; i < 4; ++i) {
                float s = acc[i] + qcr[i];
                s = fmaf(qp0r[i], pos0, s);
                s = fmaf(qp1r[i], pos1, s);
                const float p = exp2f(s * E);
                lacc[i] += p;
                sP[w][(quad*4 + i)*68 + nt*16 + lq] = (short)f2bf(p);
            }
        }

        __syncthreads();   // order sP writes before sP reads

        if (pf) {
            unsigned short tmp[16];
            *(uint4*)tmp = t0; *(uint4*)(tmp+8) = t1;
            #pragma unroll
            for (int j = 0; j < 16; ++j) sXc[bb^1][sd0+j][skey] = (short)tmp[j];
            if (tid < 128) sPos[bb^1][tid&1][tid>>1] = posreg;
        }

        #pragma unroll
        for (int kc = 0; kc < 2; ++kc) {
            U8 pa;
            const short* pp = &sP[w][lq*68 + kc*32 + quad*8];
            pa.u[0] = *(const unsigned long long*)pp;
            pa.u[1] = *(const unsigned long long*)(pp + 4);
            #pragma unroll
            for (int nt = 0; nt < 4; ++nt) {
                U8 bv;
                const short* xp = &sXc[bb][nt*16 + lq][kc*32 + quad*8];
                bv.u[0] = *(const unsigned long long*)xp;
                bv.u[1] = *(const unsigned long long*)(xp + 4);
                O[nt] = __builtin_amdgcn_mfma_f32_16x16x32_bf16(pa.v, bv.v, O[nt], 0, 0, 0);
            }
        }
        __syncthreads();
    }

    #pragma unroll
    for (int i = 0; i < 4; ++i) {
        #pragma unroll
        for (int off = 1; off < 16; off <<= 1) lacc[i] += __shfl_xor(lacc[i], off);
    }
    #pragma unroll
    for (int i = 0; i < 4; ++i) {
        const float rl = 1.f / lacc[i];
        float* orow = OPRE + ((size_t)b*NPQ + qbase + quad*4 + i)*64;
        #pragma unroll
        for (int nt = 0; nt < 4; ++nt) orow[nt*16 + lq] = O[nt][i] * rl;
    }
}

// ============================================================================
// Kernel 4 (R6): output head on MFMA. One block per batch (512 blocks).
// Chain: G1 = OPRE@W_vo + b_vo (no relu); G2 = relu(G1@nw1+nb1);
// G3 = relu(G2@nw2+nb2); z = tanh(G3.nw3 + b3). bf16 LDS ping-pong,
// encode-pattern A/B/D layouts (HW-verified). Barrier between every layer.
// ============================================================================
__global__ __launch_bounds__(256) void k_head(
    const float* __restrict__ OPRE,
    const float* __restrict__ Wvo, const float* __restrict__ bvo,
    const float* __restrict__ nw1, const float* __restrict__ nb1,
    const float* __restrict__ nw2, const float* __restrict__ nb2,
    const float* __restrict__ nw3, const float* __restrict__ nb3,
    float* __restrict__ OUT)
{
    const int tid = threadIdx.x, b = blockIdx.x;
    const int w = tid >> 6, lane = tid & 63, lq = lane & 15, quad = lane >> 4;
    __shared__ __align__(16) short sA[128][68];
    __shared__ __align__(16) short sB[128][68];
    __shared__ float sw3[64];

    // stage OPRE rows -> sA (bf16)
    for (int i = tid*4; i < 8192; i += 1024) {
        const float4 v = *(const float4*)&OPRE[(size_t)b*8192 + i];
        const int r = i >> 6, d = i & 63;
        const unsigned int u0 = (unsigned int)f2bf(v.x) | ((unsigned int)f2bf(v.y) << 16);
        const unsigned int u1 = (unsigned int)f2bf(v.z) | ((unsigned int)f2bf(v.w) << 16);
        *(uint2*)&sA[r][d] = make_uint2(u0, u1);
    }
    if (tid < 64) sw3[tid] = nw3[tid];
    __syncthreads();

    const float* Ws[3] = {Wvo, nw1, nw2};
    const float* Bs[3] = {bvo, nb1, nb2};
    for (int l = 0; l < 3; ++l) {
        const float* W = Ws[l];
        const float* Bb = Bs[l];
        bf16x8 wfrag[4][2];
        #pragma unroll
        for (int mt = 0; mt < 4; ++mt)
            #pragma unroll
            for (int kh = 0; kh < 2; ++kh)
                #pragma unroll
                for (int j = 0; j < 8; ++j)
                    wfrag[mt][kh][j] = (short)f2bf(W[(kh*32 + quad*8 + j)*64 + mt*16 + lq]);
        float be[4][4];
        #pragma unroll
        for (int mt = 0; mt < 4; ++mt)
            #pragma unroll
            for (int i = 0; i < 4; ++i) be[mt][i] = Bb[mt*16 + quad*4 + i];

        short (*src)[68] = (l & 1) ? sB : sA;
        short (*dst)[68] = (l & 1) ? sA : sB;
        const bool doRelu = (l >= 1);

        for (int bt = 0; bt < 2; ++bt) {
            U8 hb0, hb1;
            const short* hp = &src[w*32 + bt*16 + lq][0];
            hb0.u[0] = *(const unsigned long long*)(hp + quad*8);
            hb0.u[1] = *(const unsigned long long*)(hp + quad*8 + 4);
            hb1.u[0] = *(const unsigned long long*)(hp + 32 + quad*8);
            hb1.u[1] = *(const unsigned long long*)(hp + 32 + quad*8 + 4);

            f32x4 acc[4];
            #pragma unroll
            for (int mt = 0; mt < 4; ++mt) acc[mt] = (f32x4){0.f,0.f,0.f,0.f};
            #pragma unroll
            for (int mt = 0; mt < 4; ++mt) {
                acc[mt] = __builtin_amdgcn_mfma_f32_16x16x32_bf16(wfrag[mt][0], hb0.v, acc[mt], 0, 0, 0);
                acc[mt] = __builtin_amdgcn_mfma_f32_16x16x32_bf16(wfrag[mt][1], hb1.v, acc[mt], 0, 0, 0);
            }
            const int row = w*32 + bt*16 + lq;
            #pragma unroll
            for (int mt = 0; mt < 4; ++mt) {
                float v0 = acc[mt][0] + be[mt][0];
                float v1 = acc[mt][1] + be[mt][1];
                float v2 = acc[mt][2] + be[mt][2];
                float v3 = acc[mt][3] + be[mt][3];
                if (doRelu) {
                    v0 = fmaxf(v0, 0.f); v1 = fmaxf(v1, 0.f);
                    v2 = fmaxf(v2, 0.f); v3 = fmaxf(v3, 0.f);
                }
                const unsigned int u0 = (unsigned int)f2bf(v0) | ((unsigned int)f2bf(v1) << 16);
                const unsigned int u1 = (unsigned int)f2bf(v2) | ((unsigned int)f2bf(v3) << 16);
                *(uint2*)&dst[row][mt*16 + quad*4] = make_uint2(u0, u1);
            }
        }
        __syncthreads();
    }

    // final: z = tanh(G3 . nw3 + b3); G3 in sB (l=2 wrote sB)
    if (tid < 128) {
        const int row = tid;
        float acc = nb3[0];
        #pragma unroll 16
        for (int d = 0; d < 64; ++d) acc += bf2f(sB[row][d]) * sw3[d];
        OUT[(size_t)b*NPQ + row] = tanhf(acc);
    }
}

// ============================================================================
extern "C" void kernel_launch(void* const* d_in, const int* in_sizes, int n_in,
                              void* d_out, int out_size, void* d_ws, size_t ws_size,
                              hipStream_t stream)
{
    const float* pred = (const float*)d_in[0];
    const float* prey = (const float*)d_in[1];
    const float* obst = (const float*)d_in[2];
    const float* emb  = (const float*)d_in[4];
    const float* e0w1 = (const float*)d_in[5];
    const float* e0b1 = (const float*)d_in[6];
    const float* e0w2 = (const float*)d_in[7];
    const float* e0b2 = (const float*)d_in[8];
    const float* e1w1 = (const float*)d_in[9];
    const float* e1b1 = (const float*)d_in[10];
    const float* e1w2 = (const float*)d_in[11];
    const float* e1b2 = (const float*)d_in[12];
    const float* e2w1 = (const float*)d_in[13];
    const float* e2b1 = (const float*)d_in[14];
    const float* e2w2 = (const float*)d_in[15];
    const float* e2b2 = (const float*)d_in[16];
    const float* wq  = (const float*)d_in[17];
    const float* bq  = (const float*)d_in[18];
    const float* wk  = (const float*)d_in[19];
    const float* bk  = (const float*)d_in[20];
    const float* wvv = (const float*)d_in[21];
    const float* bv  = (const float*)d_in[22];
    const float* wp  = (const float*)d_in[23];
    const float* bp  = (const float*)d_in[24];
    const float* wo  = (const float*)d_in[25];
    const float* bo  = (const float*)d_in[26];
    const float* nw1 = (const float*)d_in[27];
    const float* nb1 = (const float*)d_in[28];
    const float* nw2 = (const float*)d_in[29];
    const float* nb2 = (const float*)d_in[30];
    const float* nw3 = (const float*)d_in[31];
    const float* nb3 = (const float*)d_in[32];

    char* ws = (char*)d_ws;
    unsigned short* X = (unsigned short*)ws;          // 512*1408*64 bf16 = 92,274,688 B
    float* F    = (float*)(ws + 92274688);
    float* POS  = F;                 // 1,441,792
    float* QT   = POS + 1441792;     // 4,194,304
    float* QP   = QT  + 4194304;     // 131,072
    float* QC   = QP  + 131072;      // 65,536
    float* OPRE = QC  + 65536;       // 4,194,304
    float* PREP = OPRE + 4194304;
    float* Aqk  = PREP;              // 4096
    float* a0   = Aqk + 4096;        // 64
    float* P3   = a0  + 64;          // 1024
    float* b0g0 = P3  + 1024;        // 4 (3 used)
    float* Wvo  = b0g0 + 4;          // 4096
    float* bvo  = Wvo + 4096;        // 64
    // total ~132 MB

    k_prep<<<1, 256, 0, stream>>>(emb, e0b2, e0w2, wq, bq, wk, bk, wp, bp,
        wvv, bv, wo, bo, Aqk, a0, P3, b0g0, Wvo, bvo);
    k_encode<<<5632, 256, 0, stream>>>(pred, prey, obst, emb,
        e0w1,e0b1,e0w2,e0b2, e1w1,e1b1,e1w2,e1b2, e2w1,e2b1,e2w2,e2b2, X, POS);
    k_query<<<512, 256, 0, stream>>>(pred, e0w1, e0b1, Aqk, a0, P3, b0g0,
        QT, QP, QC);
    k_attn<<<1024, 256, 0, stream>>>(X, POS, QT, QP, QC, OPRE);
    k_head<<<512, 256, 0, stream>>>(OPRE, Wvo, bvo, nw1, nb1, nw2, nb2,
        nw3, nb3, (float*)d_out);
}

// Round 7
// 335.318 us; speedup vs baseline: 1.3415x; 1.1154x over previous
//
#include <hip/hip_runtime.h>
#include <math.h>

#define NB 512
#define NPQ 128
#define NY 1024
#define NO 256
#define NTOT 1408   // NPQ+NY+NO

typedef __attribute__((ext_vector_type(8))) short bf16x8;
typedef __attribute__((ext_vector_type(4))) float f32x4;

__device__ __forceinline__ unsigned short f2bf(float f) {
    unsigned int u = __float_as_uint(f);
    u += 0x7fffu + ((u >> 16) & 1u);   // RTNE
    return (unsigned short)(u >> 16);
}
__device__ __forceinline__ float bf2f(short s) {
    return __uint_as_float(((unsigned int)(unsigned short)s) << 16);
}

union U8 { bf16x8 v; unsigned long long u[2]; };

// ============================================================================
// Kernel 0: fold weights (unchanged from R6 — verified).
// ============================================================================
__global__ __launch_bounds__(256) void k_prep(
    const float* __restrict__ emb,  const float* __restrict__ e0b2,
    const float* __restrict__ e0w2, const float* __restrict__ wq,
    const float* __restrict__ bq,   const float* __restrict__ wk,
    const float* __restrict__ bk,   const float* __restrict__ wp,
    const float* __restrict__ bp,   const float* __restrict__ wvv,
    const float* __restrict__ bv,   const float* __restrict__ wo,
    const float* __restrict__ bo,
    float* __restrict__ Aqk, float* __restrict__ a0, float* __restrict__ P3,
    float* __restrict__ b0g0, float* __restrict__ Wvo, float* __restrict__ bvo)
{
    const int tid = threadIdx.x;
    __shared__ float sW2q[4096];
    __shared__ float scq[64];

    for (int idx = tid; idx < 4096; idx += 256) {
        const int h = idx >> 6, j = idx & 63;
        float s = 0.f;
        for (int e = 0; e < 64; ++e) s += e0w2[h*64+e] * wq[e*64+j];
        sW2q[idx] = s;
    }
    if (tid < 64) {
        const int j = tid;
        float s = bq[j];
        for (int e = 0; e < 64; ++e) s += (e0b2[e] + emb[e]) * wq[e*64+j];
        scq[j] = s;
    }
    for (int idx = tid; idx < 4096; idx += 256) {
        const int e = idx >> 6, o = idx & 63;
        float s = 0.f;
        for (int d = 0; d < 64; ++d) s += wvv[e*64+d] * wo[d*64+o];
        Wvo[idx] = s;
    }
    if (tid < 64) {
        const int o = tid;
        float s = bo[o];
        for (int d = 0; d < 64; ++d) s += bv[d] * wo[d*64+o];
        bvo[o] = s;
    }
    __syncthreads();
    for (int idx = tid; idx < 4096; idx += 256) {
        const int h = idx >> 6, d = idx & 63;
        float s = 0.f;
        for (int j = 0; j < 64; ++j) s += sW2q[h*64+j] * wk[d*64+j];
        Aqk[h*64+d] = s;
    }
    if (tid < 64) {
        const int d = tid;
        float s = 0.f;
        for (int j = 0; j < 64; ++j) s += scq[j] * wk[d*64+j];
        a0[d] = s;
    }
    for (int i = tid; i < 1024; i += 256) {
        const int c = i >> 6, h = i & 63;
        float s = 0.f;
        if (c == 0 || c == 1) {
            for (int j = 0; j < 64; ++j) s += sW2q[h*64+j] * wp[c*64+j];
        } else if (c == 2) {
            for (int j = 0; j < 64; ++j) s += sW2q[h*64+j] * (bp[j] + bk[j]);
        }
        P3[i] = s;
    }
    if (tid == 0) {
        float s0 = 0.f, s1 = 0.f, s2 = 0.f;
        for (int j = 0; j < 64; ++j) {
            s0 += scq[j] * wp[j];
            s1 += scq[j] * wp[64+j];
            s2 += scq[j] * (bp[j] + bk[j]);
        }
        b0g0[0] = s0; b0g0[1] = s1; b0g0[2] = s2;
    }
}

// ============================================================================
// Kernel 1: entity encoders -> X (bf16), POS (unchanged from R4 — verified).
// ============================================================================
__global__ __launch_bounds__(256) void k_encode(
    const float* __restrict__ pred, const float* __restrict__ prey,
    const float* __restrict__ obst, const float* __restrict__ emb,
    const float* __restrict__ e0w1, const float* __restrict__ e0b1,
    const float* __restrict__ e0w2, const float* __restrict__ e0b2,
    const float* __restrict__ e1w1, const float* __restrict__ e1b1,
    const float* __restrict__ e1w2, const float* __restrict__ e1b2,
    const float* __restrict__ e2w1, const float* __restrict__ e2b1,
    const float* __restrict__ e2w2, const float* __restrict__ e2b2,
    unsigned short* __restrict__ X, float* __restrict__ POS)
{
    const int blk = blockIdx.x;
    int type, lrow0, cin, lsh, nmask, nbase;
    const float *st, *w1, *b1, *w2, *b2;
    if (blk < 512)       { type=0; lrow0=blk*128;        st=pred; w1=e0w1; b1=e0b1; w2=e0w2; b2=e0b2; cin=2; lsh=7;  nmask=NPQ-1; nbase=0; }
    else if (blk < 4608) { type=1; lrow0=(blk-512)*128;  st=prey; w1=e1w1; b1=e1b1; w2=e1w2; b2=e1b2; cin=2; lsh=10; nmask=NY-1;  nbase=NPQ; }
    else                 { type=2; lrow0=(blk-4608)*128; st=obst; w1=e2w1; b1=e2b1; w2=e2w2; b2=e2b2; cin=3; lsh=8;  nmask=NO-1;  nbase=NPQ+NY; }

    const int tid = threadIdx.x, lane = tid & 63, w = tid >> 6;
    const int lq = lane & 15, quad = lane >> 4;

    __shared__ __align__(16) short sH[4][2][16][68];

    bf16x8 wfrag[4][2];
    #pragma unroll
    for (int mt = 0; mt < 4; ++mt)
        #pragma unroll
        for (int kh = 0; kh < 2; ++kh)
            #pragma unroll
            for (int j = 0; j < 8; ++j)
                wfrag[mt][kh][j] = (short)f2bf(w2[(kh*32 + quad*8 + j)*64 + mt*16 + lq]);

    float be[4][4];
    #pragma unroll
    for (int mt = 0; mt < 4; ++mt) {
        const float4 bb4 = *(const float4*)&b2[mt*16 + quad*4];
        const float4 ee4 = *(const float4*)&emb[type*64 + mt*16 + quad*4];
        be[mt][0] = bb4.x + ee4.x; be[mt][1] = bb4.y + ee4.y;
        be[mt][2] = bb4.z + ee4.z; be[mt][3] = bb4.w + ee4.w;
    }

    const float w1r0 = w1[lane], w1r1 = w1[64+lane];
    const float w1r2 = (cin==3) ? w1[128+lane] : 0.f;
    const float b1r = b1[lane];

    {
        const int r = tid >> 1, c = tid & 1;
        const int lr = lrow0 + r;
        const int pb = lr >> lsh, n = nbase + (lr & nmask);
        POS[((size_t)pb*NTOT + n)*2 + c] = st[(size_t)lr*cin + c];
    }

    for (int rt = 0; rt < 2; ++rt) {
        const int r0 = lrow0 + w*32 + rt*16;
        const float* sp = st + (size_t)r0*cin;
        #pragma unroll
        for (int r = 0; r < 16; ++r) {
            float a = b1r + sp[r*cin]*w1r0 + sp[r*cin+1]*w1r1;
            if (cin==3) a += sp[r*cin+2]*w1r2;
            sH[w][rt][r][lane] = (short)f2bf(fmaxf(a, 0.f));
        }
        __syncthreads();

        bf16x8 hb[2];
        #pragma unroll
        for (int kh = 0; kh < 2; ++kh)
            hb[kh] = *(const bf16x8*)&sH[w][rt][lq][kh*32 + quad*8];

        f32x4 acc[4];
        #pragma unroll
        for (int mt = 0; mt < 4; ++mt) acc[mt] = (f32x4){0.f,0.f,0.f,0.f};
        #pragma unroll
        for (int mt = 0; mt < 4; ++mt) {
            acc[mt] = __builtin_amdgcn_mfma_f32_16x16x32_bf16(wfrag[mt][0], hb[0], acc[mt], 0, 0, 0);
            acc[mt] = __builtin_amdgcn_mfma_f32_16x16x32_bf16(wfrag[mt][1], hb[1], acc[mt], 0, 0, 0);
        }

        const int lr = r0 + lq;
        const int bb = lr >> lsh, n = nbase + (lr & nmask);
        unsigned short* xbase = X + ((size_t)bb*NTOT + n)*64;
        #pragma unroll
        for (int mt = 0; mt < 4; ++mt) {
            const unsigned int u0 = (unsigned int)f2bf(acc[mt][0] + be[mt][0])
                                  | ((unsigned int)f2bf(acc[mt][1] + be[mt][1]) << 16);
            const unsigned int u1 = (unsigned int)f2bf(acc[mt][2] + be[mt][2])
                                  | ((unsigned int)f2bf(acc[mt][3] + be[mt][3]) << 16);
            *(uint2*)(xbase + mt*16 + quad*4) = make_uint2(u0, u1);
        }
    }
}

// ============================================================================
// Kernel 2: queries from folded weights (unchanged from R6 — verified).
// ============================================================================
__global__ __launch_bounds__(256) void k_query(
    const float* __restrict__ pred,
    const float* __restrict__ e0w1, const float* __restrict__ e0b1,
    const float* __restrict__ Aqk,  const float* __restrict__ a0,
    const float* __restrict__ P3,   const float* __restrict__ b0g0,
    float* __restrict__ QT, float* __restrict__ QP, float* __restrict__ QC)
{
    const int tid = threadIdx.x, b = blockIdx.x;
    const int w = tid >> 6, lane = tid & 63, lq = lane & 15, quad = lane >> 4;
    __shared__ __align__(16) short sH[4][32][68];

    const float w1r0 = e0w1[lane], w1r1 = e0w1[64+lane], b1r = e0b1[lane];
    {
        const float* sp = pred + ((size_t)b*NPQ + w*32)*2;
        #pragma unroll
        for (int r = 0; r < 32; ++r) {
            const float a = b1r + sp[2*r]*w1r0 + sp[2*r+1]*w1r1;
            sH[w][r][lane] = (short)f2bf(fmaxf(a, 0.f));
        }
    }

    bf16x8 wfrag[4][2], a3[2];
    #pragma unroll
    for (int mt = 0; mt < 4; ++mt)
        #pragma unroll
        for (int kh = 0; kh < 2; ++kh)
            #pragma unroll
            for (int j = 0; j < 8; ++j)
                wfrag[mt][kh][j] = (short)f2bf(Aqk[(kh*32 + quad*8 + j)*64 + mt*16 + lq]);
    #pragma unroll
    for (int kh = 0; kh < 2; ++kh)
        #pragma unroll
        for (int j = 0; j < 8; ++j)
            a3[kh][j] = (short)f2bf(P3[lq*64 + kh*32 + quad*8 + j]);

    float4 a0r[4];
    #pragma unroll
    for (int mt = 0; mt < 4; ++mt) a0r[mt] = *(const float4*)&a0[mt*16 + quad*4];
    const float c0 = b0g0[0], c1 = b0g0[1], c2 = b0g0[2];

    __syncthreads();

    for (int bt = 0; bt < 2; ++bt) {
        U8 hb0, hb1;
        const short* hp = &sH[w][bt*16 + lq][0];
        hb0.u[0] = *(const unsigned long long*)(hp + quad*8);
        hb0.u[1] = *(const unsigned long long*)(hp + quad*8 + 4);
        hb1.u[0] = *(const unsigned long long*)(hp + 32 + quad*8);
        hb1.u[1] = *(const unsigned long long*)(hp + 32 + quad*8 + 4);

        f32x4 acc[4], acc3;
        #pragma unroll
        for (int mt = 0; mt < 4; ++mt) acc[mt] = (f32x4){0.f,0.f,0.f,0.f};
        acc3 = (f32x4){0.f,0.f,0.f,0.f};
        #pragma unroll
        for (int mt = 0; mt < 4; ++mt) {
            acc[mt] = __builtin_amdgcn_mfma_f32_16x16x32_bf16(wfrag[mt][0], hb0.v, acc[mt], 0, 0, 0);
            acc[mt] = __builtin_amdgcn_mfma_f32_16x16x32_bf16(wfrag[mt][1], hb1.v, acc[mt], 0, 0, 0);
        }
        acc3 = __builtin_amdgcn_mfma_f32_16x16x32_bf16(a3[0], hb0.v, acc3, 0, 0, 0);
        acc3 = __builtin_amdgcn_mfma_f32_16x16x32_bf16(a3[1], hb1.v, acc3, 0, 0, 0);

        const int row = b*NPQ + w*32 + bt*16 + lq;
        #pragma unroll
        for (int mt = 0; mt < 4; ++mt) {
            *(float4*)&QT[(size_t)row*64 + mt*16 + quad*4] = make_float4(
                acc[mt][0] + a0r[mt].x, acc[mt][1] + a0r[mt].y,
                acc[mt][2] + a0r[mt].z, acc[mt][3] + a0r[mt].w);
        }
        if (quad == 0) {
            const float qp0 = acc3[0] + c0, qp1 = acc3[1] + c1, qs = acc3[2] + c2;
            const float p0 = pred[(size_t)row*2], p1 = pred[(size_t)row*2 + 1];
            QP[(size_t)row*2]     = qp0;
            QP[(size_t)row*2 + 1] = qp1;
            QC[row] = qp0*p0 + qp1*p1 + qs;
        }
    }
}

// ============================================================================
// Kernel 3 (R7): flash attention, one block per batch (512), 4 waves x 32 q,
// ONE barrier per 64-key tile. Iteration i: [PV(i-1); S(i); stage X(i); barrier].
// LDS-crossing audit: sP is per-wave (same-wave WAR only: PV reads old, S
// overwrites — HW in-order DS + sched_barrier(0) forbids compiler reorder);
// all sP/sXc write->read pairs across iterations cross a __syncthreads;
// sXc parity-double-buffered (stage i writes par while PV reads par^1).
// POS read direct from global (L1-resident). Fragment layouts identical to
// R3/R4/R5-verified paths.
// ============================================================================
__global__ __launch_bounds__(256, 2) void k_attn(
    const unsigned short* __restrict__ X, const float* __restrict__ POS,
    const float* __restrict__ QT, const float* __restrict__ QP,
    const float* __restrict__ QC, float* __restrict__ OPRE)
{
    const int tid = threadIdx.x, b = blockIdx.x;
    const int w = tid >> 6, lane = tid & 63, lq = lane & 15, quad = lane >> 4;

    __shared__ __align__(16) short sXc[2][64][68];   // [buf][d][key] (X^T)
    __shared__ __align__(16) short sP[4][32][68];    // per-wave [q][key]

    // Q fragments: wave owns q rows w*32 .. w*32+31 (2 m-tiles)
    bf16x8 aq[2][2];
    #pragma unroll
    for (int qt = 0; qt < 2; ++qt) {
        const float* qrow = QT + ((size_t)b*NPQ + w*32 + qt*16 + lq)*64;
        #pragma unroll
        for (int kh = 0; kh < 2; ++kh)
            #pragma unroll
            for (int j = 0; j < 8; ++j)
                aq[qt][kh][j] = (short)f2bf(qrow[kh*32 + quad*8 + j]);
    }

    float qcr[2][4], qp0r[2][4], qp1r[2][4], lacc[2][4];
    f32x4 O[2][4];
    #pragma unroll
    for (int qt = 0; qt < 2; ++qt)
        #pragma unroll
        for (int i = 0; i < 4; ++i) {
            const size_t g = (size_t)b*NPQ + w*32 + qt*16 + quad*4 + i;
            qcr[qt][i]  = QC[g];
            qp0r[qt][i] = -QP[2*g];
            qp1r[qt][i] = -QP[2*g+1];
            lacc[qt][i] = 0.f;
        }
    #pragma unroll
    for (int qt = 0; qt < 2; ++qt)
        #pragma unroll
        for (int nt = 0; nt < 4; ++nt) O[qt][nt] = (f32x4){0.f,0.f,0.f,0.f};
    const float E = 0.180336884f;   // (1/sqrt(64)) * log2(e)

    const int skey = tid & 63, sd0 = (tid >> 6) * 16;

    for (int kt = 0; kt < 22; ++kt) {
        const int par = kt & 1;

        // prefetch X(kt) rows for the transposed staging (written post-S)
        const unsigned short* gx = X + ((size_t)b*NTOT + kt*64 + skey)*64 + sd0;
        const uint4 t0 = *(const uint4*)(gx);
        const uint4 t1 = *(const uint4*)(gx + 8);

        // ---- PV(kt-1): A = sP (own wave slice), B = sXc[par^1] ----
        if (kt > 0) {
            const int pb = par ^ 1;
            #pragma unroll
            for (int kc = 0; kc < 2; ++kc) {
                U8 pa[2];
                #pragma unroll
                for (int qt = 0; qt < 2; ++qt) {
                    const short* pp = &sP[w][qt*16 + lq][kc*32 + quad*8];
                    pa[qt].u[0] = *(const unsigned long long*)pp;
                    pa[qt].u[1] = *(const unsigned long long*)(pp + 4);
                }
                #pragma unroll
                for (int nt = 0; nt < 4; ++nt) {
                    U8 bv;
                    const short* xp = &sXc[pb][nt*16 + lq][kc*32 + quad*8];
                    bv.u[0] = *(const unsigned long long*)xp;
                    bv.u[1] = *(const unsigned long long*)(xp + 4);
                    O[0][nt] = __builtin_amdgcn_mfma_f32_16x16x32_bf16(pa[0].v, bv.v, O[0][nt], 0, 0, 0);
                    O[1][nt] = __builtin_amdgcn_mfma_f32_16x16x32_bf16(pa[1].v, bv.v, O[1][nt], 0, 0, 0);
                }
            }
        }

        // forbid compiler moving S's sP writes above PV's sP reads (same-wave WAR)
        __builtin_amdgcn_sched_barrier(0);

        // ---- S(kt): B-frags from global X rows; epilogue -> sP (own slice) ----
        #pragma unroll
        for (int nt = 0; nt < 4; ++nt) {
            union U16 { bf16x8 v; uint4 u; };
            U16 bx0, bx1;
            const unsigned short* xrow = X + ((size_t)b*NTOT + kt*64 + nt*16 + lq)*64;
            bx0.u = *(const uint4*)(xrow + quad*8);
            bx1.u = *(const uint4*)(xrow + 32 + quad*8);
            const float pos0 = POS[((size_t)b*NTOT + kt*64 + nt*16 + lq)*2];
            const float pos1 = POS[((size_t)b*NTOT + kt*64 + nt*16 + lq)*2 + 1];
            #pragma unroll
            for (int qt = 0; qt < 2; ++qt) {
                f32x4 sa = (f32x4){0.f,0.f,0.f,0.f};
                sa = __builtin_amdgcn_mfma_f32_16x16x32_bf16(aq[qt][0], bx0.v, sa, 0, 0, 0);
                sa = __builtin_amdgcn_mfma_f32_16x16x32_bf16(aq[qt][1], bx1.v, sa, 0, 0, 0);
                #pragma unroll
                for (int i = 0; i < 4; ++i) {
                    float s = sa[i] + qcr[qt][i];
                    s = fmaf(qp0r[qt][i], pos0, s);
                    s = fmaf(qp1r[qt][i], pos1, s);
                    const float p = exp2f(s * E);
                    lacc[qt][i] += p;
                    sP[w][qt*16 + quad*4 + i][nt*16 + lq] = (short)f2bf(p);
                }
            }
        }

        // ---- stage X(kt) -> sXc[par] (read by PV(kt) next iter, after barrier)
        {
            unsigned short tmp[16];
            *(uint4*)tmp = t0; *(uint4*)(tmp+8) = t1;
            #pragma unroll
            for (int j = 0; j < 16; ++j) sXc[par][sd0+j][skey] = (short)tmp[j];
        }

        __syncthreads();
    }

    // ---- final PV(21): sP and sXc[1] written pre-barrier_21 ----
    {
        #pragma unroll
        for (int kc = 0; kc < 2; ++kc) {
            U8 pa[2];
            #pragma unroll
            for (int qt = 0; qt < 2; ++qt) {
                const short* pp = &sP[w][qt*16 + lq][kc*32 + quad*8];
                pa[qt].u[0] = *(const unsigned long long*)pp;
                pa[qt].u[1] = *(const unsigned long long*)(pp + 4);
            }
            #pragma unroll
            for (int nt = 0; nt < 4; ++nt) {
                U8 bv;
                const short* xp = &sXc[1][nt*16 + lq][kc*32 + quad*8];
                bv.u[0] = *(const unsigned long long*)xp;
                bv.u[1] = *(const unsigned long long*)(xp + 4);
                O[0][nt] = __builtin_amdgcn_mfma_f32_16x16x32_bf16(pa[0].v, bv.v, O[0][nt], 0, 0, 0);
                O[1][nt] = __builtin_amdgcn_mfma_f32_16x16x32_bf16(pa[1].v, bv.v, O[1][nt], 0, 0, 0);
            }
        }
    }

    // ---- epilogue: reduce l over the 16 lq-lanes, write O/l ----
    #pragma unroll
    for (int qt = 0; qt < 2; ++qt)
        #pragma unroll
        for (int i = 0; i < 4; ++i) {
            #pragma unroll
            for (int off = 1; off < 16; off <<= 1)
                lacc[qt][i] += __shfl_xor(lacc[qt][i], off);
            const float rl = 1.f / lacc[qt][i];
            float* orow = OPRE + ((size_t)b*NPQ + w*32 + qt*16 + quad*4 + i)*64;
            #pragma unroll
            for (int nt = 0; nt < 4; ++nt) orow[nt*16 + lq] = O[qt][nt][i] * rl;
        }
}

// ============================================================================
// Kernel 4: output head (unchanged from R6 — verified).
// ============================================================================
__global__ __launch_bounds__(256) void k_head(
    const float* __restrict__ OPRE,
    const float* __restrict__ Wvo, const float* __restrict__ bvo,
    const float* __restrict__ nw1, const float* __restrict__ nb1,
    const float* __restrict__ nw2, const float* __restrict__ nb2,
    const float* __restrict__ nw3, const float* __restrict__ nb3,
    float* __restrict__ OUT)
{
    const int tid = threadIdx.x, b = blockIdx.x;
    const int w = tid >> 6, lane = tid & 63, lq = lane & 15, quad = lane >> 4;
    __shared__ __align__(16) short sA[128][68];
    __shared__ __align__(16) short sB[128][68];
    __shared__ float sw3[64];

    for (int i = tid*4; i < 8192; i += 1024) {
        const float4 v = *(const float4*)&OPRE[(size_t)b*8192 + i];
        const int r = i >> 6, d = i & 63;
        const unsigned int u0 = (unsigned int)f2bf(v.x) | ((unsigned int)f2bf(v.y) << 16);
        const unsigned int u1 = (unsigned int)f2bf(v.z) | ((unsigned int)f2bf(v.w) << 16);
        *(uint2*)&sA[r][d] = make_uint2(u0, u1);
    }
    if (tid < 64) sw3[tid] = nw3[tid];
    __syncthreads();

    const float* Ws[3] = {Wvo, nw1, nw2};
    const float* Bs[3] = {bvo, nb1, nb2};
    for (int l = 0; l < 3; ++l) {
        const float* W = Ws[l];
        const float* Bb = Bs[l];
        bf16x8 wfrag[4][2];
        #pragma unroll
        for (int mt = 0; mt < 4; ++mt)
            #pragma unroll
            for (int kh = 0; kh < 2; ++kh)
                #pragma unroll
                for (int j = 0; j < 8; ++j)
                    wfrag[mt][kh][j] = (short)f2bf(W[(kh*32 + quad*8 + j)*64 + mt*16 + lq]);
        float be[4][4];
        #pragma unroll
        for (int mt = 0; mt < 4; ++mt)
            #pragma unroll
            for (int i = 0; i < 4; ++i) be[mt][i] = Bb[mt*16 + quad*4 + i];

        short (*src)[68] = (l & 1) ? sB : sA;
        short (*dst)[68] = (l & 1) ? sA : sB;
        const bool doRelu = (l >= 1);

        for (int bt = 0; bt < 2; ++bt) {
            U8 hb0, hb1;
            const short* hp = &src[w*32 + bt*16 + lq][0];
            hb0.u[0] = *(const unsigned long long*)(hp + quad*8);
            hb0.u[1] = *(const unsigned long long*)(hp + quad*8 + 4);
            hb1.u[0] = *(const unsigned long long*)(hp + 32 + quad*8);
            hb1.u[1] = *(const unsigned long long*)(hp + 32 + quad*8 + 4);

            f32x4 acc[4];
            #pragma unroll
            for (int mt = 0; mt < 4; ++mt) acc[mt] = (f32x4){0.f,0.f,0.f,0.f};
            #pragma unroll
            for (int mt = 0; mt < 4; ++mt) {
                acc[mt] = __builtin_amdgcn_mfma_f32_16x16x32_bf16(wfrag[mt][0], hb0.v, acc[mt], 0, 0, 0);
                acc[mt] = __builtin_amdgcn_mfma_f32_16x16x32_bf16(wfrag[mt][1], hb1.v, acc[mt], 0, 0, 0);
            }
            const int row = w*32 + bt*16 + lq;
            #pragma unroll
            for (int mt = 0; mt < 4; ++mt) {
                float v0 = acc[mt][0] + be[mt][0];
                float v1 = acc[mt][1] + be[mt][1];
                float v2 = acc[mt][2] + be[mt][2];
                float v3 = acc[mt][3] + be[mt][3];
                if (doRelu) {
                    v0 = fmaxf(v0, 0.f); v1 = fmaxf(v1, 0.f);
                    v2 = fmaxf(v2, 0.f); v3 = fmaxf(v3, 0.f);
                }
                const unsigned int u0 = (unsigned int)f2bf(v0) | ((unsigned int)f2bf(v1) << 16);
                const unsigned int u1 = (unsigned int)f2bf(v2) | ((unsigned int)f2bf(v3) << 16);
                *(uint2*)&dst[row][mt*16 + quad*4] = make_uint2(u0, u1);
            }
        }
        __syncthreads();
    }

    if (tid < 128) {
        const int row = tid;
        float acc = nb3[0];
        #pragma unroll 16
        for (int d = 0; d < 64; ++d) acc += bf2f(sB[row][d]) * sw3[d];
        OUT[(size_t)b*NPQ + row] = tanhf(acc);
    }
}

// ============================================================================
extern "C" void kernel_launch(void* const* d_in, const int* in_sizes, int n_in,
                              void* d_out, int out_size, void* d_ws, size_t ws_size,
                              hipStream_t stream)
{
    const float* pred = (const float*)d_in[0];
    const float* prey = (const float*)d_in[1];
    const float* obst = (const float*)d_in[2];
    const float* emb  = (const float*)d_in[4];
    const float* e0w1 = (const float*)d_in[5];
    const float* e0b1 = (const float*)d_in[6];
    const float* e0w2 = (const float*)d_in[7];
    const float* e0b2 = (const float*)d_in[8];
    const float* e1w1 = (const float*)d_in[9];
    const float* e1b1 = (const float*)d_in[10];
    const float* e1w2 = (const float*)d_in[11];
    const float* e1b2 = (const float*)d_in[12];
    const float* e2w1 = (const float*)d_in[13];
    const float* e2b1 = (const float*)d_in[14];
    const float* e2w2 = (const float*)d_in[15];
    const float* e2b2 = (const float*)d_in[16];
    const float* wq  = (const float*)d_in[17];
    const float* bq  = (const float*)d_in[18];
    const float* wk  = (const float*)d_in[19];
    const float* bk  = (const float*)d_in[20];
    const float* wvv = (const float*)d_in[21];
    const float* bv  = (const float*)d_in[22];
    const float* wp  = (const float*)d_in[23];
    const float* bp  = (const float*)d_in[24];
    const float* wo  = (const float*)d_in[25];
    const float* bo  = (const float*)d_in[26];
    const float* nw1 = (const float*)d_in[27];
    const float* nb1 = (const float*)d_in[28];
    const float* nw2 = (const float*)d_in[29];
    const float* nb2 = (const float*)d_in[30];
    const float* nw3 = (const float*)d_in[31];
    const float* nb3 = (const float*)d_in[32];

    char* ws = (char*)d_ws;
    unsigned short* X = (unsigned short*)ws;          // 512*1408*64 bf16
    float* F    = (float*)(ws + 92274688);
    float* POS  = F;                 // 1,441,792
    float* QT   = POS + 1441792;     // 4,194,304
    float* QP   = QT  + 4194304;     // 131,072
    float* QC   = QP  + 131072;      // 65,536
    float* OPRE = QC  + 65536;       // 4,194,304
    float* PREP = OPRE + 4194304;
    float* Aqk  = PREP;              // 4096
    float* a0   = Aqk + 4096;        // 64
    float* P3   = a0  + 64;          // 1024
    float* b0g0 = P3  + 1024;        // 4 (3 used)
    float* Wvo  = b0g0 + 4;          // 4096
    float* bvo  = Wvo + 4096;        // 64

    k_prep<<<1, 256, 0, stream>>>(emb, e0b2, e0w2, wq, bq, wk, bk, wp, bp,
        wvv, bv, wo, bo, Aqk, a0, P3, b0g0, Wvo, bvo);
    k_encode<<<5632, 256, 0, stream>>>(pred, prey, obst, emb,
        e0w1,e0b1,e0w2,e0b2, e1w1,e1b1,e1w2,e1b2, e2w1,e2b1,e2w2,e2b2, X, POS);
    k_query<<<512, 256, 0, stream>>>(pred, e0w1, e0b1, Aqk, a0, P3, b0g0,
        QT, QP, QC);
    k_attn<<<512, 256, 0, stream>>>(X, POS, QT, QP, QC, OPRE);
    k_head<<<512, 256, 0, stream>>>(OPRE, Wvo, bvo, nw1, nb1, nw2, nb2,
        nw3, nb3, (float*)d_out);
}

// Round 8
// 311.822 us; speedup vs baseline: 1.4426x; 1.0754x over previous
//
#include <hip/hip_runtime.h>
#include <math.h>

#define NB 512
#define NPQ 128
#define NY 1024
#define NO 256
#define NTOT 1408   // NPQ+NY+NO

typedef __attribute__((ext_vector_type(8))) short bf16x8;
typedef __attribute__((ext_vector_type(4))) float f32x4;

__device__ __forceinline__ unsigned short f2bf(float f) {
    unsigned int u = __float_as_uint(f);
    u += 0x7fffu + ((u >> 16) & 1u);   // RTNE
    return (unsigned short)(u >> 16);
}
__device__ __forceinline__ float bf2f(short s) {
    return __uint_as_float(((unsigned int)(unsigned short)s) << 16);
}

union U8 { bf16x8 v; unsigned long long u[2]; };

// ============================================================================
// Kernel 0: fold weights (R6-verified) + R8: pre-pack encoder w2 into bf16
// MFMA-A-frag order (W2P) and BEP = b2 + emb (f32).
// W2P layout: for (t,mt,kh,lane): 8 bf16 at ((t*4+mt)*2+kh)*64*8 + lane*8,
//   value j: w2_t[(kh*32 + (lane>>4)*8 + j)*64 + mt*16 + (lane&15)].
// ============================================================================
__global__ __launch_bounds__(256) void k_prep(
    const float* __restrict__ emb,  const float* __restrict__ e0b2,
    const float* __restrict__ e0w2, const float* __restrict__ wq,
    const float* __restrict__ bq,   const float* __restrict__ wk,
    const float* __restrict__ bk,   const float* __restrict__ wp,
    const float* __restrict__ bp,   const float* __restrict__ wvv,
    const float* __restrict__ bv,   const float* __restrict__ wo,
    const float* __restrict__ bo,
    const float* __restrict__ e1b2, const float* __restrict__ e1w2,
    const float* __restrict__ e2b2, const float* __restrict__ e2w2,
    float* __restrict__ Aqk, float* __restrict__ a0, float* __restrict__ P3,
    float* __restrict__ b0g0, float* __restrict__ Wvo, float* __restrict__ bvo,
    unsigned short* __restrict__ W2P, float* __restrict__ BEP)
{
    const int tid = threadIdx.x;
    __shared__ float sW2q[4096];
    __shared__ float scq[64];

    // ---- W2P pre-pack: 1536 items of 8 bf16 ----
    const float* w2s[3] = {e0w2, e1w2, e2w2};
    for (int idx = tid; idx < 1536; idx += 256) {
        const int t = idx >> 9, rem = idx & 511;
        const int mt = rem >> 7, rem2 = rem & 127;
        const int kh = rem2 >> 6, lane = rem2 & 63;
        const int quad = lane >> 4, lq = lane & 15;
        const float* w2 = w2s[t];
        unsigned short v[8];
        #pragma unroll
        for (int j = 0; j < 8; ++j)
            v[j] = f2bf(w2[(kh*32 + quad*8 + j)*64 + mt*16 + lq]);
        unsigned int u[4];
        #pragma unroll
        for (int p = 0; p < 4; ++p)
            u[p] = (unsigned int)v[2*p] | ((unsigned int)v[2*p+1] << 16);
        *(uint4*)&W2P[(size_t)idx*8] = make_uint4(u[0], u[1], u[2], u[3]);
    }
    // ---- BEP = b2 + emb ----
    const float* b2s[3] = {e0b2, e1b2, e2b2};
    for (int idx = tid; idx < 192; idx += 256) {
        const int t = idx >> 6, d = idx & 63;
        BEP[idx] = b2s[t][d] + emb[t*64 + d];
    }

    for (int idx = tid; idx < 4096; idx += 256) {
        const int h = idx >> 6, j = idx & 63;
        float s = 0.f;
        for (int e = 0; e < 64; ++e) s += e0w2[h*64+e] * wq[e*64+j];
        sW2q[idx] = s;
    }
    if (tid < 64) {
        const int j = tid;
        float s = bq[j];
        for (int e = 0; e < 64; ++e) s += (e0b2[e] + emb[e]) * wq[e*64+j];
        scq[j] = s;
    }
    for (int idx = tid; idx < 4096; idx += 256) {
        const int e = idx >> 6, o = idx & 63;
        float s = 0.f;
        for (int d = 0; d < 64; ++d) s += wvv[e*64+d] * wo[d*64+o];
        Wvo[idx] = s;
    }
    if (tid < 64) {
        const int o = tid;
        float s = bo[o];
        for (int d = 0; d < 64; ++d) s += bv[d] * wo[d*64+o];
        bvo[o] = s;
    }
    __syncthreads();
    for (int idx = tid; idx < 4096; idx += 256) {
        const int h = idx >> 6, d = idx & 63;
        float s = 0.f;
        for (int j = 0; j < 64; ++j) s += sW2q[h*64+j] * wk[d*64+j];
        Aqk[h*64+d] = s;
    }
    if (tid < 64) {
        const int d = tid;
        float s = 0.f;
        for (int j = 0; j < 64; ++j) s += scq[j] * wk[d*64+j];
        a0[d] = s;
    }
    for (int i = tid; i < 1024; i += 256) {
        const int c = i >> 6, h = i & 63;
        float s = 0.f;
        if (c == 0 || c == 1) {
            for (int j = 0; j < 64; ++j) s += sW2q[h*64+j] * wp[c*64+j];
        } else if (c == 2) {
            for (int j = 0; j < 64; ++j) s += sW2q[h*64+j] * (bp[j] + bk[j]);
        }
        P3[i] = s;
    }
    if (tid == 0) {
        float s0 = 0.f, s1 = 0.f, s2 = 0.f;
        for (int j = 0; j < 64; ++j) {
            s0 += scq[j] * wp[j];
            s1 += scq[j] * wp[64+j];
            s2 += scq[j] * (bp[j] + bk[j]);
        }
        b0g0[0] = s0; b0g0[1] = s1; b0g0[2] = s2;
    }
}

// ============================================================================
// Kernel 1 (R8): entity encoders, registers-only. No LDS, no barriers.
// Layer-1 computed straight into MFMA B-frag registers: lane (lq,quad)
// computes h1[row=lq][k=kh*32+quad*8+j]. w2 A-frags loaded pre-packed from
// W2P (one 16B load per frag). Same f2bf(MFMA + b2+emb) numerics as R4-R7.
// ============================================================================
__global__ __launch_bounds__(256) void k_encode(
    const float* __restrict__ pred, const float* __restrict__ prey,
    const float* __restrict__ obst,
    const unsigned short* __restrict__ W2P, const float* __restrict__ BEP,
    const float* __restrict__ e0w1, const float* __restrict__ e0b1,
    const float* __restrict__ e1w1, const float* __restrict__ e1b1,
    const float* __restrict__ e2w1, const float* __restrict__ e2b1,
    unsigned short* __restrict__ X, float* __restrict__ POS)
{
    const int blk = blockIdx.x;
    int type, lrow0, cin, lsh, nmask, nbase;
    const float *st, *w1, *b1;
    if (blk < 512)       { type=0; lrow0=blk*128;        st=pred; w1=e0w1; b1=e0b1; cin=2; lsh=7;  nmask=NPQ-1; nbase=0; }
    else if (blk < 4608) { type=1; lrow0=(blk-512)*128;  st=prey; w1=e1w1; b1=e1b1; cin=2; lsh=10; nmask=NY-1;  nbase=NPQ; }
    else                 { type=2; lrow0=(blk-4608)*128; st=obst; w1=e2w1; b1=e2b1; cin=3; lsh=8;  nmask=NO-1;  nbase=NPQ+NY; }

    const int tid = threadIdx.x, lane = tid & 63, w = tid >> 6;
    const int lq = lane & 15, quad = lane >> 4;

    // ---- w2 A-frags: pre-packed, one 16B load each ----
    bf16x8 wfrag[4][2];
    #pragma unroll
    for (int mt = 0; mt < 4; ++mt)
        #pragma unroll
        for (int kh = 0; kh < 2; ++kh)
            wfrag[mt][kh] = *(const bf16x8*)&W2P[(size_t)(((type*4 + mt)*2 + kh)*64 + lane)*8];

    // ---- bias+emb (f32, pre-summed) ----
    float4 be[4];
    #pragma unroll
    for (int mt = 0; mt < 4; ++mt)
        be[mt] = *(const float4*)&BEP[type*64 + mt*16 + quad*4];

    // ---- layer-1 params for this lane's 16 k-values ----
    float b1v[2][8], w0v[2][8], w1v[2][8], w2v[2][8];
    #pragma unroll
    for (int kh = 0; kh < 2; ++kh) {
        const int k0 = kh*32 + quad*8;
        *(float4*)&b1v[kh][0] = *(const float4*)&b1[k0];
        *(float4*)&b1v[kh][4] = *(const float4*)&b1[k0+4];
        *(float4*)&w0v[kh][0] = *(const float4*)&w1[k0];
        *(float4*)&w0v[kh][4] = *(const float4*)&w1[k0+4];
        *(float4*)&w1v[kh][0] = *(const float4*)&w1[64+k0];
        *(float4*)&w1v[kh][4] = *(const float4*)&w1[64+k0+4];
        if (cin == 3) {
            *(float4*)&w2v[kh][0] = *(const float4*)&w1[128+k0];
            *(float4*)&w2v[kh][4] = *(const float4*)&w1[128+k0+4];
        }
    }

    // ---- POS: one store per thread covers 128 rows x 2 coords ----
    {
        const int r = tid >> 1, c = tid & 1;
        const int lr = lrow0 + r;
        const int pb = lr >> lsh, n = nbase + (lr & nmask);
        POS[((size_t)pb*NTOT + n)*2 + c] = st[(size_t)lr*cin + c];
    }

    #pragma unroll
    for (int rt = 0; rt < 2; ++rt) {
        const int lr = lrow0 + w*32 + rt*16 + lq;    // this lane's entity row
        // per-lane state load
        float s0, s1, s2 = 0.f;
        if (cin == 2) {
            const float2 sv = *(const float2*)&st[(size_t)lr*2];
            s0 = sv.x; s1 = sv.y;
        } else {
            const float2 sv = *(const float2*)&st[(size_t)lr*3];
            s0 = sv.x; s1 = sv.y; s2 = st[(size_t)lr*3 + 2];
        }
        // layer-1 direct to B-frag registers
        bf16x8 hb[2];
        #pragma unroll
        for (int kh = 0; kh < 2; ++kh)
            #pragma unroll
            for (int j = 0; j < 8; ++j) {
                float a = b1v[kh][j] + s0*w0v[kh][j] + s1*w1v[kh][j];
                if (cin == 3) a += s2*w2v[kh][j];
                hb[kh][j] = (short)f2bf(fmaxf(a, 0.f));
            }

        f32x4 acc[4];
        #pragma unroll
        for (int mt = 0; mt < 4; ++mt) acc[mt] = (f32x4){0.f,0.f,0.f,0.f};
        #pragma unroll
        for (int mt = 0; mt < 4; ++mt) {
            acc[mt] = __builtin_amdgcn_mfma_f32_16x16x32_bf16(wfrag[mt][0], hb[0], acc[mt], 0, 0, 0);
            acc[mt] = __builtin_amdgcn_mfma_f32_16x16x32_bf16(wfrag[mt][1], hb[1], acc[mt], 0, 0, 0);
        }

        // store: D col=lane&15 = entity row (= lr); lane holds d = mt*16+quad*4+i
        const int bb = lr >> lsh, n = nbase + (lr & nmask);
        unsigned short* xbase = X + ((size_t)bb*NTOT + n)*64;
        #pragma unroll
        for (int mt = 0; mt < 4; ++mt) {
            const unsigned int u0 = (unsigned int)f2bf(acc[mt][0] + be[mt].x)
                                  | ((unsigned int)f2bf(acc[mt][1] + be[mt].y) << 16);
            const unsigned int u1 = (unsigned int)f2bf(acc[mt][2] + be[mt].z)
                                  | ((unsigned int)f2bf(acc[mt][3] + be[mt].w) << 16);
            *(uint2*)(xbase + mt*16 + quad*4) = make_uint2(u0, u1);
        }
    }
}

// ============================================================================
// Kernel 2: queries from folded weights (unchanged from R6 — verified).
// ============================================================================
__global__ __launch_bounds__(256) void k_query(
    const float* __restrict__ pred,
    const float* __restrict__ e0w1, const float* __restrict__ e0b1,
    const float* __restrict__ Aqk,  const float* __restrict__ a0,
    const float* __restrict__ P3,   const float* __restrict__ b0g0,
    float* __restrict__ QT, float* __restrict__ QP, float* __restrict__ QC)
{
    const int tid = threadIdx.x, b = blockIdx.x;
    const int w = tid >> 6, lane = tid & 63, lq = lane & 15, quad = lane >> 4;
    __shared__ __align__(16) short sH[4][32][68];

    const float w1r0 = e0w1[lane], w1r1 = e0w1[64+lane], b1r = e0b1[lane];
    {
        const float* sp = pred + ((size_t)b*NPQ + w*32)*2;
        #pragma unroll
        for (int r = 0; r < 32; ++r) {
            const float a = b1r + sp[2*r]*w1r0 + sp[2*r+1]*w1r1;
            sH[w][r][lane] = (short)f2bf(fmaxf(a, 0.f));
        }
    }

    bf16x8 wfrag[4][2], a3[2];
    #pragma unroll
    for (int mt = 0; mt < 4; ++mt)
        #pragma unroll
        for (int kh = 0; kh < 2; ++kh)
            #pragma unroll
            for (int j = 0; j < 8; ++j)
                wfrag[mt][kh][j] = (short)f2bf(Aqk[(kh*32 + quad*8 + j)*64 + mt*16 + lq]);
    #pragma unroll
    for (int kh = 0; kh < 2; ++kh)
        #pragma unroll
        for (int j = 0; j < 8; ++j)
            a3[kh][j] = (short)f2bf(P3[lq*64 + kh*32 + quad*8 + j]);

    float4 a0r[4];
    #pragma unroll
    for (int mt = 0; mt < 4; ++mt) a0r[mt] = *(const float4*)&a0[mt*16 + quad*4];
    const float c0 = b0g0[0], c1 = b0g0[1], c2 = b0g0[2];

    __syncthreads();

    for (int bt = 0; bt < 2; ++bt) {
        U8 hb0, hb1;
        const short* hp = &sH[w][bt*16 + lq][0];
        hb0.u[0] = *(const unsigned long long*)(hp + quad*8);
        hb0.u[1] = *(const unsigned long long*)(hp + quad*8 + 4);
        hb1.u[0] = *(const unsigned long long*)(hp + 32 + quad*8);
        hb1.u[1] = *(const unsigned long long*)(hp + 32 + quad*8 + 4);

        f32x4 acc[4], acc3;
        #pragma unroll
        for (int mt = 0; mt < 4; ++mt) acc[mt] = (f32x4){0.f,0.f,0.f,0.f};
        acc3 = (f32x4){0.f,0.f,0.f,0.f};
        #pragma unroll
        for (int mt = 0; mt < 4; ++mt) {
            acc[mt] = __builtin_amdgcn_mfma_f32_16x16x32_bf16(wfrag[mt][0], hb0.v, acc[mt], 0, 0, 0);
            acc[mt] = __builtin_amdgcn_mfma_f32_16x16x32_bf16(wfrag[mt][1], hb1.v, acc[mt], 0, 0, 0);
        }
        acc3 = __builtin_amdgcn_mfma_f32_16x16x32_bf16(a3[0], hb0.v, acc3, 0, 0, 0);
        acc3 = __builtin_amdgcn_mfma_f32_16x16x32_bf16(a3[1], hb1.v, acc3, 0, 0, 0);

        const int row = b*NPQ + w*32 + bt*16 + lq;
        #pragma unroll
        for (int mt = 0; mt < 4; ++mt) {
            *(float4*)&QT[(size_t)row*64 + mt*16 + quad*4] = make_float4(
                acc[mt][0] + a0r[mt].x, acc[mt][1] + a0r[mt].y,
                acc[mt][2] + a0r[mt].z, acc[mt][3] + a0r[mt].w);
        }
        if (quad == 0) {
            const float qp0 = acc3[0] + c0, qp1 = acc3[1] + c1, qs = acc3[2] + c2;
            const float p0 = pred[(size_t)row*2], p1 = pred[(size_t)row*2 + 1];
            QP[(size_t)row*2]     = qp0;
            QP[(size_t)row*2 + 1] = qp1;
            QC[row] = qp0*p0 + qp1*p1 + qs;
        }
    }
}

// ============================================================================
// Kernel 3: flash attention (unchanged from R7 — verified).
// ============================================================================
__global__ __launch_bounds__(256, 2) void k_attn(
    const unsigned short* __restrict__ X, const float* __restrict__ POS,
    const float* __restrict__ QT, const float* __restrict__ QP,
    const float* __restrict__ QC, float* __restrict__ OPRE)
{
    const int tid = threadIdx.x, b = blockIdx.x;
    const int w = tid >> 6, lane = tid & 63, lq = lane & 15, quad = lane >> 4;

    __shared__ __align__(16) short sXc[2][64][68];   // [buf][d][key] (X^T)
    __shared__ __align__(16) short sP[4][32][68];    // per-wave [q][key]

    bf16x8 aq[2][2];
    #pragma unroll
    for (int qt = 0; qt < 2; ++qt) {
        const float* qrow = QT + ((size_t)b*NPQ + w*32 + qt*16 + lq)*64;
        #pragma unroll
        for (int kh = 0; kh < 2; ++kh)
            #pragma unroll
            for (int j = 0; j < 8; ++j)
                aq[qt][kh][j] = (short)f2bf(qrow[kh*32 + quad*8 + j]);
    }

    float qcr[2][4], qp0r[2][4], qp1r[2][4], lacc[2][4];
    f32x4 O[2][4];
    #pragma unroll
    for (int qt = 0; qt < 2; ++qt)
        #pragma unroll
        for (int i = 0; i < 4; ++i) {
            const size_t g = (size_t)b*NPQ + w*32 + qt*16 + quad*4 + i;
            qcr[qt][i]  = QC[g];
            qp0r[qt][i] = -QP[2*g];
            qp1r[qt][i] = -QP[2*g+1];
            lacc[qt][i] = 0.f;
        }
    #pragma unroll
    for (int qt = 0; qt < 2; ++qt)
        #pragma unroll
        for (int nt = 0; nt < 4; ++nt) O[qt][nt] = (f32x4){0.f,0.f,0.f,0.f};
    const float E = 0.180336884f;   // (1/sqrt(64)) * log2(e)

    const int skey = tid & 63, sd0 = (tid >> 6) * 16;

    for (int kt = 0; kt < 22; ++kt) {
        const int par = kt & 1;

        const unsigned short* gx = X + ((size_t)b*NTOT + kt*64 + skey)*64 + sd0;
        const uint4 t0 = *(const uint4*)(gx);
        const uint4 t1 = *(const uint4*)(gx + 8);

        if (kt > 0) {
            const int pb = par ^ 1;
            #pragma unroll
            for (int kc = 0; kc < 2; ++kc) {
                U8 pa[2];
                #pragma unroll
                for (int qt = 0; qt < 2; ++qt) {
                    const short* pp = &sP[w][qt*16 + lq][kc*32 + quad*8];
                    pa[qt].u[0] = *(const unsigned long long*)pp;
                    pa[qt].u[1] = *(const unsigned long long*)(pp + 4);
                }
                #pragma unroll
                for (int nt = 0; nt < 4; ++nt) {
                    U8 bv;
                    const short* xp = &sXc[pb][nt*16 + lq][kc*32 + quad*8];
                    bv.u[0] = *(const unsigned long long*)xp;
                    bv.u[1] = *(const unsigned long long*)(xp + 4);
                    O[0][nt] = __builtin_amdgcn_mfma_f32_16x16x32_bf16(pa[0].v, bv.v, O[0][nt], 0, 0, 0);
                    O[1][nt] = __builtin_amdgcn_mfma_f32_16x16x32_bf16(pa[1].v, bv.v, O[1][nt], 0, 0, 0);
                }
            }
        }

        __builtin_amdgcn_sched_barrier(0);

        #pragma unroll
        for (int nt = 0; nt < 4; ++nt) {
            union U16 { bf16x8 v; uint4 u; };
            U16 bx0, bx1;
            const unsigned short* xrow = X + ((size_t)b*NTOT + kt*64 + nt*16 + lq)*64;
            bx0.u = *(const uint4*)(xrow + quad*8);
            bx1.u = *(const uint4*)(xrow + 32 + quad*8);
            const float pos0 = POS[((size_t)b*NTOT + kt*64 + nt*16 + lq)*2];
            const float pos1 = POS[((size_t)b*NTOT + kt*64 + nt*16 + lq)*2 + 1];
            #pragma unroll
            for (int qt = 0; qt < 2; ++qt) {
                f32x4 sa = (f32x4){0.f,0.f,0.f,0.f};
                sa = __builtin_amdgcn_mfma_f32_16x16x32_bf16(aq[qt][0], bx0.v, sa, 0, 0, 0);
                sa = __builtin_amdgcn_mfma_f32_16x16x32_bf16(aq[qt][1], bx1.v, sa, 0, 0, 0);
                #pragma unroll
                for (int i = 0; i < 4; ++i) {
                    float s = sa[i] + qcr[qt][i];
                    s = fmaf(qp0r[qt][i], pos0, s);
                    s = fmaf(qp1r[qt][i], pos1, s);
                    const float p = exp2f(s * E);
                    lacc[qt][i] += p;
                    sP[w][qt*16 + quad*4 + i][nt*16 + lq] = (short)f2bf(p);
                }
            }
        }

        {
            unsigned short tmp[16];
            *(uint4*)tmp = t0; *(uint4*)(tmp+8) = t1;
            #pragma unroll
            for (int j = 0; j < 16; ++j) sXc[par][sd0+j][skey] = (short)tmp[j];
        }

        __syncthreads();
    }

    {
        #pragma unroll
        for (int kc = 0; kc < 2; ++kc) {
            U8 pa[2];
            #pragma unroll
            for (int qt = 0; qt < 2; ++qt) {
                const short* pp = &sP[w][qt*16 + lq][kc*32 + quad*8];
                pa[qt].u[0] = *(const unsigned long long*)pp;
                pa[qt].u[1] = *(const unsigned long long*)(pp + 4);
            }
            #pragma unroll
            for (int nt = 0; nt < 4; ++nt) {
                U8 bv;
                const short* xp = &sXc[1][nt*16 + lq][kc*32 + quad*8];
                bv.u[0] = *(const unsigned long long*)xp;
                bv.u[1] = *(const unsigned long long*)(xp + 4);
                O[0][nt] = __builtin_amdgcn_mfma_f32_16x16x32_bf16(pa[0].v, bv.v, O[0][nt], 0, 0, 0);
                O[1][nt] = __builtin_amdgcn_mfma_f32_16x16x32_bf16(pa[1].v, bv.v, O[1][nt], 0, 0, 0);
            }
        }
    }

    #pragma unroll
    for (int qt = 0; qt < 2; ++qt)
        #pragma unroll
        for (int i = 0; i < 4; ++i) {
            #pragma unroll
            for (int off = 1; off < 16; off <<= 1)
                lacc[qt][i] += __shfl_xor(lacc[qt][i], off);
            const float rl = 1.f / lacc[qt][i];
            float* orow = OPRE + ((size_t)b*NPQ + w*32 + qt*16 + quad*4 + i)*64;
            #pragma unroll
            for (int nt = 0; nt < 4; ++nt) orow[nt*16 + lq] = O[qt][nt][i] * rl;
        }
}

// ============================================================================
// Kernel 4: output head (unchanged from R6 — verified).
// ============================================================================
__global__ __launch_bounds__(256) void k_head(
    const float* __restrict__ OPRE,
    const float* __restrict__ Wvo, const float* __restrict__ bvo,
    const float* __restrict__ nw1, const float* __restrict__ nb1,
    const float* __restrict__ nw2, const float* __restrict__ nb2,
    const float* __restrict__ nw3, const float* __restrict__ nb3,
    float* __restrict__ OUT)
{
    const int tid = threadIdx.x, b = blockIdx.x;
    const int w = tid >> 6, lane = tid & 63, lq = lane & 15, quad = lane >> 4;
    __shared__ __align__(16) short sA[128][68];
    __shared__ __align__(16) short sB[128][68];
    __shared__ float sw3[64];

    for (int i = tid*4; i < 8192; i += 1024) {
        const float4 v = *(const float4*)&OPRE[(size_t)b*8192 + i];
        const int r = i >> 6, d = i & 63;
        const unsigned int u0 = (unsigned int)f2bf(v.x) | ((unsigned int)f2bf(v.y) << 16);
        const unsigned int u1 = (unsigned int)f2bf(v.z) | ((unsigned int)f2bf(v.w) << 16);
        *(uint2*)&sA[r][d] = make_uint2(u0, u1);
    }
    if (tid < 64) sw3[tid] = nw3[tid];
    __syncthreads();

    const float* Ws[3] = {Wvo, nw1, nw2};
    const float* Bs[3] = {bvo, nb1, nb2};
    for (int l = 0; l < 3; ++l) {
        const float* W = Ws[l];
        const float* Bb = Bs[l];
        bf16x8 wfrag[4][2];
        #pragma unroll
        for (int mt = 0; mt < 4; ++mt)
            #pragma unroll
            for (int kh = 0; kh < 2; ++kh)
                #pragma unroll
                for (int j = 0; j < 8; ++j)
                    wfrag[mt][kh][j] = (short)f2bf(W[(kh*32 + quad*8 + j)*64 + mt*16 + lq]);
        float be[4][4];
        #pragma unroll
        for (int mt = 0; mt < 4; ++mt)
            #pragma unroll
            for (int i = 0; i < 4; ++i) be[mt][i] = Bb[mt*16 + quad*4 + i];

        short (*src)[68] = (l & 1) ? sB : sA;
        short (*dst)[68] = (l & 1) ? sA : sB;
        const bool doRelu = (l >= 1);

        for (int bt = 0; bt < 2; ++bt) {
            U8 hb0, hb1;
            const short* hp = &src[w*32 + bt*16 + lq][0];
            hb0.u[0] = *(const unsigned long long*)(hp + quad*8);
            hb0.u[1] = *(const unsigned long long*)(hp + quad*8 + 4);
            hb1.u[0] = *(const unsigned long long*)(hp + 32 + quad*8);
            hb1.u[1] = *(const unsigned long long*)(hp + 32 + quad*8 + 4);

            f32x4 acc[4];
            #pragma unroll
            for (int mt = 0; mt < 4; ++mt) acc[mt] = (f32x4){0.f,0.f,0.f,0.f};
            #pragma unroll
            for (int mt = 0; mt < 4; ++mt) {
                acc[mt] = __builtin_amdgcn_mfma_f32_16x16x32_bf16(wfrag[mt][0], hb0.v, acc[mt], 0, 0, 0);
                acc[mt] = __builtin_amdgcn_mfma_f32_16x16x32_bf16(wfrag[mt][1], hb1.v, acc[mt], 0, 0, 0);
            }
            const int row = w*32 + bt*16 + lq;
            #pragma unroll
            for (int mt = 0; mt < 4; ++mt) {
                float v0 = acc[mt][0] + be[mt][0];
                float v1 = acc[mt][1] + be[mt][1];
                float v2 = acc[mt][2] + be[mt][2];
                float v3 = acc[mt][3] + be[mt][3];
                if (doRelu) {
                    v0 = fmaxf(v0, 0.f); v1 = fmaxf(v1, 0.f);
                    v2 = fmaxf(v2, 0.f); v3 = fmaxf(v3, 0.f);
                }
                const unsigned int u0 = (unsigned int)f2bf(v0) | ((unsigned int)f2bf(v1) << 16);
                const unsigned int u1 = (unsigned int)f2bf(v2) | ((unsigned int)f2bf(v3) << 16);
                *(uint2*)&dst[row][mt*16 + quad*4] = make_uint2(u0, u1);
            }
        }
        __syncthreads();
    }

    if (tid < 128) {
        const int row = tid;
        float acc = nb3[0];
        #pragma unroll 16
        for (int d = 0; d < 64; ++d) acc += bf2f(sB[row][d]) * sw3[d];
        OUT[(size_t)b*NPQ + row] = tanhf(acc);
    }
}

// ============================================================================
extern "C" void kernel_launch(void* const* d_in, const int* in_sizes, int n_in,
                              void* d_out, int out_size, void* d_ws, size_t ws_size,
                              hipStream_t stream)
{
    const float* pred = (const float*)d_in[0];
    const float* prey = (const float*)d_in[1];
    const float* obst = (const float*)d_in[2];
    const float* emb  = (const float*)d_in[4];
    const float* e0w1 = (const float*)d_in[5];
    const float* e0b1 = (const float*)d_in[6];
    const float* e0w2 = (const float*)d_in[7];
    const float* e0b2 = (const float*)d_in[8];
    const float* e1w1 = (const float*)d_in[9];
    const float* e1b1 = (const float*)d_in[10];
    const float* e1w2 = (const float*)d_in[11];
    const float* e1b2 = (const float*)d_in[12];
    const float* e2w1 = (const float*)d_in[13];
    const float* e2b1 = (const float*)d_in[14];
    const float* e2w2 = (const float*)d_in[15];
    const float* e2b2 = (const float*)d_in[16];
    const float* wq  = (const float*)d_in[17];
    const float* bq  = (const float*)d_in[18];
    const float* wk  = (const float*)d_in[19];
    const float* bk  = (const float*)d_in[20];
    const float* wvv = (const float*)d_in[21];
    const float* bv  = (const float*)d_in[22];
    const float* wp  = (const float*)d_in[23];
    const float* bp  = (const float*)d_in[24];
    const float* wo  = (const float*)d_in[25];
    const float* bo  = (const float*)d_in[26];
    const float* nw1 = (const float*)d_in[27];
    const float* nb1 = (const float*)d_in[28];
    const float* nw2 = (const float*)d_in[29];
    const float* nb2 = (const float*)d_in[30];
    const float* nw3 = (const float*)d_in[31];
    const float* nb3 = (const float*)d_in[32];

    char* ws = (char*)d_ws;
    unsigned short* X = (unsigned short*)ws;          // 512*1408*64 bf16
    float* F    = (float*)(ws + 92274688);
    float* POS  = F;                 // 1,441,792
    float* QT   = POS + 1441792;     // 4,194,304
    float* QP   = QT  + 4194304;     // 131,072
    float* QC   = QP  + 131072;      // 65,536
    float* OPRE = QC  + 65536;       // 4,194,304
    float* PREP = OPRE + 4194304;
    float* Aqk  = PREP;              // 4096
    float* a0   = Aqk + 4096;        // 64
    float* P3   = a0  + 64;          // 1024
    float* b0g0 = P3  + 1024;        // 4 (3 used)
    float* Wvo  = b0g0 + 4;          // 4096
    float* bvo  = Wvo + 4096;        // 64
    unsigned short* W2P = (unsigned short*)(bvo + 64);   // 12288 bf16
    float* BEP  = (float*)(W2P + 12288);                 // 192 f32

    k_prep<<<1, 256, 0, stream>>>(emb, e0b2, e0w2, wq, bq, wk, bk, wp, bp,
        wvv, bv, wo, bo, e1b2, e1w2, e2b2, e2w2,
        Aqk, a0, P3, b0g0, Wvo, bvo, W2P, BEP);
    k_encode<<<5632, 256, 0, stream>>>(pred, prey, obst, W2P, BEP,
        e0w1, e0b1, e1w1, e1b1, e2w1, e2b1, X, POS);
    k_query<<<512, 256, 0, stream>>>(pred, e0w1, e0b1, Aqk, a0, P3, b0g0,
        QT, QP, QC);
    k_attn<<<512, 256, 0, stream>>>(X, POS, QT, QP, QC, OPRE);
    k_head<<<512, 256, 0, stream>>>(OPRE, Wvo, bvo, nw1, nb1, nw2, nb2,
        nw3, nb3, (float*)d_out);
}